// Round 15
// baseline (308.297 us; speedup 1.0000x reference)
//
#include <hip/hip_runtime.h>
#include <math.h>

#define NQ    32768
#define DDIM  256
#define NCLS  3
#define CELLS 512
#define STOT  1536   // NCLS*CELLS
#define BK    32     // K-step for all GEMM kernels (k_pe LDS 80KB, others 64KB)

typedef __attribute__((ext_vector_type(8)))  short bf16x8;
typedef __attribute__((ext_vector_type(16))) float f32x16;

// C-fragment row map for 32x32 MFMA: row = (r&3) + 8*(r>>2) + 4*(lane>>5)
#define ROWF(r) (((r) & 3) + 8 * ((r) >> 2) + 4 * lh)

// counted-vmcnt pipeline barriers (T4): wait only until the CURRENT buffer's
// loads are done (N = next buffer's loads stay in flight), then barrier.
#define PIPE_WAIT_BAR(N) asm volatile("s_waitcnt vmcnt(" #N ")\n\ts_barrier" ::: "memory")
#define PIPE_BAR()       asm volatile("s_barrier" ::: "memory")

__device__ __forceinline__ f32x16 mfma16(bf16x8 a, bf16x8 b, f32x16 c) {
    return __builtin_amdgcn_mfma_f32_32x32x16_bf16(a, b, c, 0, 0, 0);
}
__device__ __forceinline__ unsigned short f2bf(float f) {   // RNE
    const unsigned u = __float_as_uint(f);
    return (unsigned short)((u + 0x7FFFu + ((u >> 16) & 1u)) >> 16);
}
__device__ __forceinline__ float bf2f(unsigned short b) {
    return __uint_as_float(((unsigned)b) << 16);
}
// sum 16 bf16 lanes of two bf16x8 regs in fp32
__device__ __forceinline__ float sum16(bf16x8 w0, bf16x8 w1) {
    float s = 0.f;
#pragma unroll
    for (int e = 0; e < 8; ++e)
        s += bf2f((unsigned short)w0[e]) + bf2f((unsigned short)w1[e]);
    return s;
}
// async global->LDS, 16B per lane; lds dest = wave-uniform base + lane*16
__device__ __forceinline__ void gl16(const unsigned short* g, unsigned short* l) {
    __builtin_amdgcn_global_load_lds(
        (const __attribute__((address_space(1))) unsigned int*)g,
        (__attribute__((address_space(3))) unsigned int*)l, 16, 0, 0);
}

// ---- class histogram (3 atomics per wave) ----
__global__ __launch_bounds__(256) void k_count(const int* __restrict__ labels,
        unsigned* __restrict__ cnt) {
    const int i = blockIdx.x * 256 + threadIdx.x;
    const int lane = threadIdx.x & 63;
    const int c = labels[i];
    const unsigned long long m0 = __ballot(c == 0), m1 = __ballot(c == 1);
    if (lane == 0) {
        const unsigned n0 = __popcll(m0), n1 = __popcll(m1);
        atomicAdd(&cnt[0], n0);
        atomicAdd(&cnt[1], n1);
        atomicAdd(&cnt[2], 64u - n0 - n1);
    }
}

// ---- stable-ish scatter into class-sorted order (3 atomics per wave) ----
__global__ __launch_bounds__(256) void k_scatter(const int* __restrict__ labels,
        const unsigned* __restrict__ cnt, unsigned* __restrict__ wcnt,
        int* __restrict__ idx) {
    const int i = blockIdx.x * 256 + threadIdx.x;
    const int lane = threadIdx.x & 63;
    const int c = labels[i];
    const unsigned long long m0 = __ballot(c == 0), m1 = __ballot(c == 1),
                             m2 = __ballot(c == 2);
    const unsigned long long mym = (c == 0) ? m0 : (c == 1) ? m1 : m2;
    const unsigned long long ltm = ((unsigned long long)1 << lane) - 1;
    const unsigned rank = __popcll(mym & ltm);
    int b0 = 0, b1 = 0, b2 = 0;
    if (lane == 0) {
        b0 = (int)atomicAdd(&wcnt[0], __popcll(m0));
        b1 = (int)atomicAdd(&wcnt[1], __popcll(m1));
        b2 = (int)atomicAdd(&wcnt[2], __popcll(m2));
    }
    b0 = __shfl(b0, 0, 64); b1 = __shfl(b1, 0, 64); b2 = __shfl(b2, 0, 64);
    const unsigned base = (c == 0) ? (unsigned)b0
                        : (c == 1) ? cnt[0] + (unsigned)b1
                                   : cnt[0] + cnt[1] + (unsigned)b2;
    idx[base + rank] = i;
}

// ---- unified convert (Q gathered into class-sorted order; M direct) ----
// R x 256 fp32 -> hi/lo bf16 (row-major) + transposed hi + row sumsq
__global__ __launch_bounds__(256) void k_conv2(const float* __restrict__ Q,
        const float* __restrict__ M, const int* __restrict__ idx,
        unsigned short* __restrict__ Qhi, unsigned short* __restrict__ Qlo,
        unsigned short* __restrict__ QhiT, float* __restrict__ qn2,
        unsigned short* __restrict__ Mhi, unsigned short* __restrict__ Mlo,
        unsigned short* __restrict__ MhiT, float* __restrict__ mn2) {
    __shared__ unsigned short lh_s[64][65];
    const int bq = NQ / 64;
    const bool isQ = (int)blockIdx.x < bq;
    const float* src        = isQ ? Q    : M;
    unsigned short* hi      = isQ ? Qhi  : Mhi;
    unsigned short* lo      = isQ ? Qlo  : Mlo;
    unsigned short* hiT     = isQ ? QhiT : MhiT;
    float* sq               = isQ ? qn2  : mn2;
    const int R             = isQ ? NQ   : STOT;
    const int r0 = (isQ ? blockIdx.x : blockIdx.x - bq) * 64;
    const int k0 = blockIdx.y * 64, t = threadIdx.x;
#pragma unroll
    for (int it = 0; it < 4; ++it) {
        const int idxl = t + 256 * it;
        const int rl = idxl >> 4, kq = idxl & 15;
        const int orow = isQ ? idx[r0 + rl] : (r0 + rl);
        const float4 v = *(const float4*)(src + (size_t)orow * DDIM + k0 + kq * 4);
        const unsigned short h0 = f2bf(v.x), h1 = f2bf(v.y), h2 = f2bf(v.z), h3 = f2bf(v.w);
        const unsigned short l0 = f2bf(v.x - bf2f(h0)), l1 = f2bf(v.y - bf2f(h1));
        const unsigned short l2 = f2bf(v.z - bf2f(h2)), l3 = f2bf(v.w - bf2f(h3));
        ushort4 hv; hv.x = h0; hv.y = h1; hv.z = h2; hv.w = h3;
        ushort4 lv; lv.x = l0; lv.y = l1; lv.z = l2; lv.w = l3;
        *(ushort4*)(hi + (size_t)(r0 + rl) * DDIM + k0 + kq * 4) = hv;
        *(ushort4*)(lo + (size_t)(r0 + rl) * DDIM + k0 + kq * 4) = lv;
        lh_s[rl][kq * 4 + 0] = h0; lh_s[rl][kq * 4 + 1] = h1;
        lh_s[rl][kq * 4 + 2] = h2; lh_s[rl][kq * 4 + 3] = h3;
        float ssq = v.x * v.x + v.y * v.y + v.z * v.z + v.w * v.w;
        ssq += __shfl_xor(ssq, 1, 64);
        ssq += __shfl_xor(ssq, 2, 64);
        ssq += __shfl_xor(ssq, 4, 64);
        ssq += __shfl_xor(ssq, 8, 64);
        if (kq == 0) atomicAdd(&sq[r0 + rl], ssq);
    }
    __syncthreads();
#pragma unroll
    for (int it = 0; it < 16; ++it) {
        const int idxl = t + 256 * it;          // 0..4095
        const int kl = idxl >> 6, rl = idxl & 63;
        hiT[(size_t)(k0 + kl) * R + r0 + rl] = lh_s[rl][kl];
    }
}

// ---- main GEMM pass (128i x 192j tile, dbuf 80KB LDS, counted-vmcnt, swizzle) ----
// logits -> P' (row-shift) + E' (class-range masked, transposed, SKIPPED when
// the fragment's sorted-i range misses the class range).
__global__ __launch_bounds__(256) void k_pe(
        const unsigned short* __restrict__ Qhi, const unsigned short* __restrict__ Qlo,
        const unsigned short* __restrict__ Mhi, const unsigned short* __restrict__ Mlo,
        const unsigned* __restrict__ cnt, const float* __restrict__ qn2,
        const float* __restrict__ mn2,
        unsigned short* __restrict__ P, unsigned short* __restrict__ ET,
        float* __restrict__ rowsum, float* __restrict__ colsum,
        int ibase, int ch, int ipg) {
    __shared__ unsigned short sA[2][2][128][BK];   // [buf][hi/lo] Q tile, 32 KB
    __shared__ unsigned short sB[2][2][192][BK];   // [buf][hi/lo] M tile, 48 KB
    typedef unsigned short trt[32][40];
    trt* trP = (trt*)&sA[0][0][0][0];   // epilogue overlay on sA (10 KB)
    trt* trE = trP + 4;                 // next 10 KB (20 KB <= 32 KB)

    const int t = threadIdx.x, lane = t & 63, wid = t >> 6;
    const int l31 = lane & 31, lh = lane >> 5;
    const int wi = wid >> 1, wj = wid & 1;
    int ib, jb;
    if (ipg > 0) {
        const int xcd = blockIdx.x & 7, s = blockIdx.x >> 3;
        jb = s & 7; ib = xcd * ipg + (s >> 3);
    } else { jb = blockIdx.x % 8; ib = blockIdx.x / 8; }
    const int iblk = ib * 128, jblk = jb * 192;
    const int iloc0 = iblk + wi * 64;
    const int j0    = jblk + wj * 96;

    const unsigned short* gA[2] = { Qhi + (size_t)(ibase + iblk) * DDIM,
                                    Qlo + (size_t)(ibase + iblk) * DDIM };
    const unsigned short* gB[2] = { Mhi + (size_t)jblk * DDIM,
                                    Mlo + (size_t)jblk * DDIM };
    auto STAGE = [&](int b, int k0) {   // 10 gl16 per thread
#pragma unroll
        for (int h = 0; h < 2; ++h) {
#pragma unroll
            for (int it = 0; it < 2; ++it) {               // A: 512 chunks
                const int c = wid * 128 + it * 64 + lane;
                const int r = c >> 2, o = ((c ^ (c >> 3)) & 3) * 8;
                gl16(gA[h] + (size_t)r * DDIM + k0 + o, &sA[b][h][0][0] + c * 8);
            }
#pragma unroll
            for (int it = 0; it < 3; ++it) {               // B: 768 chunks
                const int c = wid * 192 + it * 64 + lane;
                const int r = c >> 2, o = ((c ^ (c >> 3)) & 3) * 8;
                gl16(gB[h] + (size_t)r * DDIM + k0 + o, &sB[b][h][0][0] + c * 8);
            }
        }
    };

    f32x16 acc[2][3] = {};
    const int ra0 = wi * 64 + l31, ra1 = ra0 + 32;
    const int rb0 = wj * 96 + l31, rb1 = rb0 + 32, rb2 = rb0 + 64;
    const int swa = (ra0 >> 1) & 3;   // same for +32/+64 row offsets
    const int swb = (rb0 >> 1) & 3;
    auto COMPUTE = [&](int b) {
#pragma unroll
        for (int t16 = 0; t16 < 2; ++t16) {
            const int oc = t16 * 2 + lh;    // k-group 0..3
            const int ka = (oc ^ swa) * 8, kb = (oc ^ swb) * 8;
            const bf16x8 a0h = *(const bf16x8*)&sA[b][0][ra0][ka];
            const bf16x8 a1h = *(const bf16x8*)&sA[b][0][ra1][ka];
            const bf16x8 a0l = *(const bf16x8*)&sA[b][1][ra0][ka];
            const bf16x8 a1l = *(const bf16x8*)&sA[b][1][ra1][ka];
            const bf16x8 b0h = *(const bf16x8*)&sB[b][0][rb0][kb];
            const bf16x8 b1h = *(const bf16x8*)&sB[b][0][rb1][kb];
            const bf16x8 b2h = *(const bf16x8*)&sB[b][0][rb2][kb];
            const bf16x8 b0l = *(const bf16x8*)&sB[b][1][rb0][kb];
            const bf16x8 b1l = *(const bf16x8*)&sB[b][1][rb1][kb];
            const bf16x8 b2l = *(const bf16x8*)&sB[b][1][rb2][kb];
            acc[0][0] = mfma16(a0h, b0h, acc[0][0]);
            acc[0][0] = mfma16(a0h, b0l, acc[0][0]);
            acc[0][0] = mfma16(a0l, b0h, acc[0][0]);
            acc[0][1] = mfma16(a0h, b1h, acc[0][1]);
            acc[0][1] = mfma16(a0h, b1l, acc[0][1]);
            acc[0][1] = mfma16(a0l, b1h, acc[0][1]);
            acc[0][2] = mfma16(a0h, b2h, acc[0][2]);
            acc[0][2] = mfma16(a0h, b2l, acc[0][2]);
            acc[0][2] = mfma16(a0l, b2h, acc[0][2]);
            acc[1][0] = mfma16(a1h, b0h, acc[1][0]);
            acc[1][0] = mfma16(a1h, b0l, acc[1][0]);
            acc[1][0] = mfma16(a1l, b0h, acc[1][0]);
            acc[1][1] = mfma16(a1h, b1h, acc[1][1]);
            acc[1][1] = mfma16(a1h, b1l, acc[1][1]);
            acc[1][1] = mfma16(a1l, b1h, acc[1][1]);
            acc[1][2] = mfma16(a1h, b2h, acc[1][2]);
            acc[1][2] = mfma16(a1h, b2l, acc[1][2]);
            acc[1][2] = mfma16(a1l, b2h, acc[1][2]);
        }
    };

    STAGE(0, 0);
    STAGE(1, BK);
    for (int s = 0; s < DDIM / BK - 1; ++s) {
        PIPE_WAIT_BAR(10);                  // buf s ready; buf s+1 in flight
        COMPUTE(s & 1);
        PIPE_BAR();                         // all waves done reading buf s
        if (s + 2 < DDIM / BK) STAGE(s & 1, (s + 2) * BK);
    }
    PIPE_WAIT_BAR(0);
    COMPUTE(1);                             // last step (odd index)
    __syncthreads();   // full drain before trP/trE overlay

    // class ranges in sorted-index space
    const int sC1 = (int)cnt[0], sC2 = sC1 + (int)cnt[1];
    // per-lane per-tj scale: em = exp(96 - mn)
    float em3[3];
#pragma unroll
    for (int tj = 0; tj < 3; ++tj)
        em3[tj] = __expf(96.0f - 6.0f * sqrtf(mn2[j0 + tj * 32 + l31]));

    float rsum[2] = {0.f, 0.f};
    float csum[3] = {0.f, 0.f, 0.f};
#pragma unroll
    for (int ti = 0; ti < 2; ++ti) {
        float qn[16], eq[16];
        const int ig0 = ibase + iloc0 + ti * 32;
#pragma unroll
        for (int r = 0; r < 16; ++r) {
            const int ir = ig0 + ROWF(r);
            qn[r] = 6.0f * sqrtf(qn2[ir]);
            eq[r] = __expf(qn[r] - 96.0f);
        }
#pragma unroll
        for (int tj = 0; tj < 3; ++tj) {
            const int c = (j0 + tj * 32) >> 9;   // class of this 32-col frag
            const int sc = (c == 0) ? 0 : (c == 1) ? sC1 : sC2;
            const int ec = (c == 0) ? sC1 : (c == 1) ? sC2 : NQ;
            const int lo = max(sc - ibase, 0), hi = min(ec - ibase, ch);
            const int klo = lo & ~63, khi = (hi + 63) & ~63;
            const int L0 = iloc0 + ti * 32;
            const bool doE = (lo < hi) && (L0 < khi) && (L0 + 32 > klo);
            const float em = em3[tj];
#pragma unroll
            for (int r = 0; r < 16; r += 2) {
                const float p0 = __expf(acc[ti][tj][r] - qn[r]);
                const float p1 = __expf(acc[ti][tj][r + 1] - qn[r + 1]);
                trP[wid][ROWF(r)][l31]     = f2bf(p0);
                trP[wid][ROWF(r + 1)][l31] = f2bf(p1);
                if (doE) {
                    const int i0r = ig0 + ROWF(r), i1r = ig0 + ROWF(r + 1);
                    const float e0 = (i0r >= sc && i0r < ec) ? p0 * eq[r] * em : 0.f;
                    const float e1 = (i1r >= sc && i1r < ec) ? p1 * eq[r + 1] * em : 0.f;
                    const unsigned pk = (unsigned)f2bf(e0) | ((unsigned)f2bf(e1) << 16);
                    *(unsigned*)&trE[wid][l31][ROWF(r)] = pk;
                }
            }
            const int rr = lane >> 1, off = (lane & 1) * 16;
            {   // P: row rr (i-local sorted), 16 contiguous j
                const unsigned short* lp = &trP[wid][rr][off];
                const bf16x8 w0 = *(const bf16x8*)(lp);
                const bf16x8 w1 = *(const bf16x8*)(lp + 8);
                unsigned short* prow = P + (size_t)(iloc0 + ti * 32 + rr) * STOT
                                         + j0 + tj * 32 + off;
                *(bf16x8*)(prow)     = w0;
                *(bf16x8*)(prow + 8) = w1;
                rsum[ti] += sum16(w0, w1);
            }
            if (doE) {   // ET: row rr (j-local), 16 contiguous sorted-i
                const unsigned short* lp = &trE[wid][rr][off];
                const bf16x8 w0 = *(const bf16x8*)(lp);
                const bf16x8 w1 = *(const bf16x8*)(lp + 8);
                unsigned short* erow = ET + (size_t)(j0 + tj * 32 + rr) * ch
                                          + iloc0 + ti * 32 + off;
                *(bf16x8*)(erow)     = w0;
                *(bf16x8*)(erow + 8) = w1;
                csum[tj] += sum16(w0, w1);
            }
        }
    }
    {
        const int rr = lane >> 1;
#pragma unroll
        for (int ti = 0; ti < 2; ++ti) {
            const float v = rsum[ti] + __shfl_xor(rsum[ti], 1, 64);
            if ((lane & 1) == 0)
                atomicAdd(&rowsum[ibase + iloc0 + ti * 32 + rr], v);
        }
#pragma unroll
        for (int tj = 0; tj < 3; ++tj) {
            const float v = csum[tj] + __shfl_xor(csum[tj], 1, 64);
            if ((lane & 1) == 0)
                atomicAdd(&colsum[j0 + tj * 32 + rr], v);
        }
    }
}

// ---- PV (dbuf, BK=64, counted-vmcnt, 128x128 tile); out scattered via idx ----
__global__ __launch_bounds__(256) void k_pv(const unsigned short* __restrict__ P,
        const unsigned short* __restrict__ MhiT, const float* __restrict__ rowsum,
        const int* __restrict__ idx, float* __restrict__ out, int ibase) {
    __shared__ unsigned short sP[2][128][64];   // 32 KB
    __shared__ unsigned short sV[2][128][64];   // 32 KB
    const int t = threadIdx.x, lane = t & 63, wid = t >> 6;
    const int l31 = lane & 31, lh = lane >> 5;
    const int wq = wid >> 1, wd = wid & 1;
    const int qblk = blockIdx.x * 128, dblk = blockIdx.y * 128;
    const unsigned short* gP = P + (size_t)qblk * STOT;
    const unsigned short* gV = MhiT + (size_t)dblk * STOT;

    auto STAGE = [&](int b, int k0) {   // 8 gl16 per thread
#pragma unroll
        for (int it = 0; it < 4; ++it) {
            const int c = wid * 256 + it * 64 + lane;
            const int r = c >> 3, o = ((c & 7) ^ (r & 7)) * 8;
            gl16(gP + (size_t)r * STOT + k0 + o, &sP[b][0][0] + c * 8);
            gl16(gV + (size_t)r * STOT + k0 + o, &sV[b][0][0] + c * 8);
        }
    };

    f32x16 acc[2][2] = {};
    const int rp0 = wq * 64 + l31, rp1 = rp0 + 32;
    const int rv0 = wd * 64 + l31, rv1 = rv0 + 32;
    auto COMPUTE = [&](int b) {
#pragma unroll
        for (int t16 = 0; t16 < 4; ++t16) {
            const int oc = t16 * 2 + lh;
            const bf16x8 a0 = *(const bf16x8*)&sP[b][rp0][(oc ^ (rp0 & 7)) * 8];
            const bf16x8 a1 = *(const bf16x8*)&sP[b][rp1][(oc ^ (rp1 & 7)) * 8];
            const bf16x8 b0 = *(const bf16x8*)&sV[b][rv0][(oc ^ (rv0 & 7)) * 8];
            const bf16x8 b1 = *(const bf16x8*)&sV[b][rv1][(oc ^ (rv1 & 7)) * 8];
            acc[0][0] = mfma16(a0, b0, acc[0][0]);
            acc[0][1] = mfma16(a0, b1, acc[0][1]);
            acc[1][0] = mfma16(a1, b0, acc[1][0]);
            acc[1][1] = mfma16(a1, b1, acc[1][1]);
        }
    };

    STAGE(0, 0);
    STAGE(1, 64);
    for (int s = 0; s < STOT / 64 - 1; ++s) {
        PIPE_WAIT_BAR(8);
        COMPUTE(s & 1);
        PIPE_BAR();
        if (s + 2 < STOT / 64) STAGE(s & 1, (s + 2) * 64);
    }
    PIPE_WAIT_BAR(0);
    COMPUTE(1);                             // step 23 (odd)

    float riv[2][16];
#pragma unroll
    for (int tq = 0; tq < 2; ++tq)
#pragma unroll
        for (int r = 0; r < 16; ++r)
            riv[tq][r] = 1.f / rowsum[ibase + qblk + wq * 64 + tq * 32 + ROWF(r)];
#pragma unroll
    for (int tq = 0; tq < 2; ++tq) {
#pragma unroll
        for (int td = 0; td < 2; ++td) {
#pragma unroll
            for (int r = 0; r < 16; ++r) {
                const int sp = ibase + qblk + wq * 64 + tq * 32 + ROWF(r);
                const int od = dblk + wd * 64 + td * 32 + l31;
                out[(size_t)idx[sp] * DDIM + od] = acc[tq][td][r] * riv[tq][r];
            }
        }
    }
}

// ---- delta (dbuf, BK=64, counted-vmcnt, dynamic class K-range, XCD remap) ----
__global__ __launch_bounds__(256) void k_delta4(const unsigned short* __restrict__ ET,
        const unsigned short* __restrict__ QhiT, const unsigned* __restrict__ cnt,
        float* __restrict__ delta, int ibase, int ch, int ksplit, int ppx) {
    __shared__ unsigned short sE[2][128][64];   // 32 KB
    __shared__ unsigned short sQ[2][128][64];   // 32 KB
    const int t = threadIdx.x, lane = t & 63, wid = t >> 6;
    const int l31 = lane & 31, lh = lane >> 5;
    const int wj = wid >> 1, wd = wid & 1;
    int jb, db, kb;
    if (ppx > 0) {
        const int xcd = blockIdx.x & 7, s = blockIdx.x >> 3;
        jb = s % 12;
        const int pidx = xcd * ppx + s / 12;
        kb = pidx >> 1; db = pidx & 1;
    } else {
        jb = blockIdx.x % 12; db = (blockIdx.x / 12) & 1; kb = blockIdx.x / 24;
    }
    const int jblk = jb * 128, dblk = db * 128;
    const int j0 = jblk + wj * 64, d0 = dblk + wd * 64;

    // dynamic K-range = padded chunk-local class range
    const int c = jblk >> 9;
    const int sC1 = (int)cnt[0], sC2 = sC1 + (int)cnt[1];
    const int sc = (c == 0) ? 0 : (c == 1) ? sC1 : sC2;
    const int ec = (c == 0) ? sC1 : (c == 1) ? sC2 : NQ;
    const int lo = max(sc - ibase, 0), hi = min(ec - ibase, ch);
    if (lo >= hi) return;
    const int klo = lo & ~63, khi = (hi + 63) & ~63;
    const int itot = (khi - klo) >> 6;
    const int per = (itot + ksplit - 1) / ksplit;
    const int myn = min(per, itot - kb * per);
    if (myn <= 0) return;
    const int st = klo + kb * per * 64;

    const unsigned short* gE = ET + (size_t)jblk * ch + st;
    const unsigned short* gQ = QhiT + (size_t)dblk * NQ + ibase + st;

    auto STAGE = [&](int b, int k0) {   // 8 gl16 per thread
#pragma unroll
        for (int it = 0; it < 4; ++it) {
            const int cc = wid * 256 + it * 64 + lane;
            const int r = cc >> 3, o = ((cc & 7) ^ (r & 7)) * 8;
            gl16(gE + (size_t)r * ch + k0 + o, &sE[b][0][0] + cc * 8);
            gl16(gQ + (size_t)r * NQ + k0 + o, &sQ[b][0][0] + cc * 8);
        }
    };

    f32x16 acc[2][2] = {};
    const int re0 = wj * 64 + l31, re1 = re0 + 32;
    const int rq0 = wd * 64 + l31, rq1 = rq0 + 32;
    auto COMPUTE = [&](int b) {
#pragma unroll
        for (int t16 = 0; t16 < 4; ++t16) {
            const int oc = t16 * 2 + lh;
            const bf16x8 a0 = *(const bf16x8*)&sE[b][re0][(oc ^ (re0 & 7)) * 8];
            const bf16x8 a1 = *(const bf16x8*)&sE[b][re1][(oc ^ (re1 & 7)) * 8];
            const bf16x8 b0 = *(const bf16x8*)&sQ[b][rq0][(oc ^ (rq0 & 7)) * 8];
            const bf16x8 b1 = *(const bf16x8*)&sQ[b][rq1][(oc ^ (rq1 & 7)) * 8];
            acc[0][0] = mfma16(a0, b0, acc[0][0]);
            acc[0][1] = mfma16(a0, b1, acc[0][1]);
            acc[1][0] = mfma16(a1, b0, acc[1][0]);
            acc[1][1] = mfma16(a1, b1, acc[1][1]);
        }
    };

    STAGE(0, 0);
    if (myn > 1) STAGE(1, 64);
    for (int s = 0; s < myn - 1; ++s) {
        PIPE_WAIT_BAR(8);
        COMPUTE(s & 1);
        PIPE_BAR();
        if (s + 2 < myn) STAGE(s & 1, (s + 2) * 64);
    }
    PIPE_WAIT_BAR(0);
    COMPUTE((myn - 1) & 1);

#pragma unroll
    for (int tj = 0; tj < 2; ++tj) {
#pragma unroll
        for (int td = 0; td < 2; ++td) {
#pragma unroll
            for (int r = 0; r < 16; ++r) {
                const int jr = j0 + tj * 32 + ROWF(r);
                atomicAdd(&delta[(size_t)jr * DDIM + d0 + td * 32 + l31], acc[tj][td][r]);
            }
        }
    }
}

// ---- finalize memory: new = M + delta/colsum, row-normalize ----
__global__ void k_final(const float* __restrict__ M,
                        const float* __restrict__ delta,
                        const float* __restrict__ colsum,
                        float* __restrict__ out) {
    const int row  = blockIdx.x * 4 + (threadIdx.x >> 6);
    const int lane = threadIdx.x & 63;
    const float inv = 1.f / colsum[row];
    const float4 mv = *(const float4*)(M + (size_t)row * DDIM + lane * 4);
    const float4 dv = *(const float4*)(delta + (size_t)row * DDIM + lane * 4);
    float4 nv;
    nv.x = fmaf(dv.x, inv, mv.x);
    nv.y = fmaf(dv.y, inv, mv.y);
    nv.z = fmaf(dv.z, inv, mv.z);
    nv.w = fmaf(dv.w, inv, mv.w);
    float ss = nv.x * nv.x + nv.y * nv.y + nv.z * nv.z + nv.w * nv.w;
#pragma unroll
    for (int sh = 1; sh < 64; sh <<= 1) ss += __shfl_xor(ss, sh, 64);
    const float rn = 1.f / fmaxf(sqrtf(ss), 1e-12f);
    nv.x *= rn; nv.y *= rn; nv.z *= rn; nv.w *= rn;
    *(float4*)(out + (size_t)NQ * DDIM + (size_t)row * DDIM + lane * 4) = nv;
}

extern "C" void kernel_launch(void* const* d_in, const int* in_sizes, int n_in,
                              void* d_out, int out_size, void* d_ws, size_t ws_size,
                              hipStream_t stream) {
    const float* Q      = (const float*)d_in[0];
    const int*   labels = (const int*)d_in[1];
    const float* M      = (const float*)d_in[2];
    float* out = (float*)d_out;

    // ---- workspace layout (memset region first) ----
    char* p = (char*)d_ws;
    float* colsum = (float*)p;          p += (size_t)STOT * 4;
    float* delta  = (float*)p;          p += (size_t)STOT * DDIM * 4;
    float* qn2    = (float*)p;          p += (size_t)NQ * 4;
    float* mn2    = (float*)p;          p += (size_t)STOT * 4;
    float* rowsum = (float*)p;          p += (size_t)NQ * 4;
    unsigned* cnt  = (unsigned*)p;      p += 4 * 4;
    unsigned* wcnt = (unsigned*)p;      p += 4 * 4;
    const size_t zero_bytes = (size_t)(p - (char*)d_ws);
    int* idx = (int*)p;                 p += (size_t)NQ * 4;
    unsigned short* Qhi  = (unsigned short*)p; p += (size_t)NQ * DDIM * 2;
    unsigned short* Qlo  = (unsigned short*)p; p += (size_t)NQ * DDIM * 2;
    unsigned short* QhiT = (unsigned short*)p; p += (size_t)NQ * DDIM * 2;
    unsigned short* Mhi  = (unsigned short*)p; p += (size_t)STOT * DDIM * 2;
    unsigned short* Mlo  = (unsigned short*)p; p += (size_t)STOT * DDIM * 2;
    unsigned short* MhiT = (unsigned short*)p; p += (size_t)STOT * DDIM * 2;
    const size_t fixed_bytes = (size_t)(p - (char*)d_ws);

    // adaptive chunking: P' (ch x 1536) + ET (1536 x ch), both bf16; ch % 1024 == 0
    int nch = 2;
    while (nch < 32 &&
           fixed_bytes + (size_t)(NQ / nch) * STOT * 2 * 2 > ws_size) nch <<= 1;
    const int ch = NQ / nch;
    unsigned short* Pbuf = (unsigned short*)p;
    unsigned short* ETb  = Pbuf + (size_t)ch * STOT;

    const int ipg    = ((ch / 128) % 8 == 0) ? (ch / 128) / 8 : 0;
    const int ksplit = ch / 1024;
    const int ppx    = ((2 * ksplit) % 8 == 0) ? (2 * ksplit) / 8 : 0;

    hipMemsetAsync(d_ws, 0, zero_bytes, stream);

    k_count<<<NQ / 256, 256, 0, stream>>>(labels, cnt);
    k_scatter<<<NQ / 256, 256, 0, stream>>>(labels, cnt, wcnt, idx);
    k_conv2<<<dim3(NQ / 64 + STOT / 64, 4), 256, 0, stream>>>(
        Q, M, idx, Qhi, Qlo, QhiT, qn2, Mhi, Mlo, MhiT, mn2);

    for (int h = 0; h < nch; ++h) {
        const int ibase = h * ch;
        k_pe<<<8 * (ch / 128), 256, 0, stream>>>(Qhi, Qlo, Mhi, Mlo, cnt,
                                                 qn2, mn2, Pbuf, ETb, rowsum, colsum,
                                                 ibase, ch, ipg);
        k_pv<<<dim3(ch / 128, 2), 256, 0, stream>>>(Pbuf, MhiT, rowsum, idx, out, ibase);
        k_delta4<<<24 * ksplit, 256, 0, stream>>>(ETb, QhiT, cnt, delta,
                                                  ibase, ch, ksplit, ppx);
    }
    k_final<<<STOT / 4, 256, 0, stream>>>(M, delta, colsum, out);
}

// Round 16
// 250.913 us; speedup vs baseline: 1.2287x; 1.2287x over previous
//
#include <hip/hip_runtime.h>
#include <math.h>

#define NQ    32768
#define DDIM  256
#define NCLS  3
#define CELLS 512
#define STOT  1536   // NCLS*CELLS
#define BK    32     // K-step for all GEMM kernels

typedef __attribute__((ext_vector_type(8)))  short bf16x8;
typedef __attribute__((ext_vector_type(8)))  _Float16 f16x8;
typedef __attribute__((ext_vector_type(16))) float f32x16;

// C-fragment row map for 32x32 MFMA: row = (r&3) + 8*(r>>2) + 4*(lane>>5)
#define ROWF(r) (((r) & 3) + 8 * ((r) >> 2) + 4 * lh)

// counted-vmcnt pipeline barriers (T4)
#define PIPE_WAIT_BAR(N) asm volatile("s_waitcnt vmcnt(" #N ")\n\ts_barrier" ::: "memory")
#define PIPE_BAR()       asm volatile("s_barrier" ::: "memory")

__device__ __forceinline__ f32x16 mfma16(bf16x8 a, bf16x8 b, f32x16 c) {
    return __builtin_amdgcn_mfma_f32_32x32x16_bf16(a, b, c, 0, 0, 0);
}
__device__ __forceinline__ f32x16 mfma16h(f16x8 a, f16x8 b, f32x16 c) {
    return __builtin_amdgcn_mfma_f32_32x32x16_f16(a, b, c, 0, 0, 0);
}
__device__ __forceinline__ unsigned short f2bf(float f) {   // RNE
    const unsigned u = __float_as_uint(f);
    return (unsigned short)((u + 0x7FFFu + ((u >> 16) & 1u)) >> 16);
}
__device__ __forceinline__ float bf2f(unsigned short b) {
    return __uint_as_float(((unsigned)b) << 16);
}
__device__ __forceinline__ unsigned short h2u(_Float16 h) {
    union { _Float16 h; unsigned short u; } v; v.h = h; return v.u;
}
// sum 16 bf16 lanes of two bf16x8 regs in fp32
__device__ __forceinline__ float sum16(bf16x8 w0, bf16x8 w1) {
    float s = 0.f;
#pragma unroll
    for (int e = 0; e < 8; ++e)
        s += bf2f((unsigned short)w0[e]) + bf2f((unsigned short)w1[e]);
    return s;
}
// async global->LDS, 16B per lane; lds dest = wave-uniform base + lane*16
__device__ __forceinline__ void gl16(const unsigned short* g, unsigned short* l) {
    __builtin_amdgcn_global_load_lds(
        (const __attribute__((address_space(1))) unsigned int*)g,
        (__attribute__((address_space(3))) unsigned int*)l, 16, 0, 0);
}

// ---- unified convert: Q and M in one launch ----
// R x 256 fp32 -> fp16 hi/lo (row-major, for QK^T) + transposed bf16 + row sumsq
__global__ __launch_bounds__(256) void k_conv2(const float* __restrict__ Q,
        const float* __restrict__ M,
        unsigned short* __restrict__ Qh16, unsigned short* __restrict__ Ql16,
        unsigned short* __restrict__ QhiT, float* __restrict__ qn2,
        unsigned short* __restrict__ Mh16, unsigned short* __restrict__ Ml16,
        unsigned short* __restrict__ MhiT, float* __restrict__ mn2) {
    __shared__ unsigned short lh_s[64][65];
    const int bq = NQ / 64;
    const bool isQ = (int)blockIdx.x < bq;
    const float* src        = isQ ? Q    : M;
    unsigned short* hi      = isQ ? Qh16 : Mh16;
    unsigned short* lo      = isQ ? Ql16 : Ml16;
    unsigned short* hiT     = isQ ? QhiT : MhiT;
    float* sq               = isQ ? qn2  : mn2;
    const int R             = isQ ? NQ   : STOT;
    const int r0 = (isQ ? blockIdx.x : blockIdx.x - bq) * 64;
    const int k0 = blockIdx.y * 64, t = threadIdx.x;
#pragma unroll
    for (int it = 0; it < 4; ++it) {
        const int idx = t + 256 * it;
        const int rl = idx >> 4, kq = idx & 15;
        const float4 v = *(const float4*)(src + (size_t)(r0 + rl) * DDIM + k0 + kq * 4);
        const _Float16 h0 = (_Float16)v.x, h1 = (_Float16)v.y;
        const _Float16 h2 = (_Float16)v.z, h3 = (_Float16)v.w;
        const _Float16 l0 = (_Float16)(v.x - (float)h0), l1 = (_Float16)(v.y - (float)h1);
        const _Float16 l2 = (_Float16)(v.z - (float)h2), l3 = (_Float16)(v.w - (float)h3);
        ushort4 hv; hv.x = h2u(h0); hv.y = h2u(h1); hv.z = h2u(h2); hv.w = h2u(h3);
        ushort4 lv; lv.x = h2u(l0); lv.y = h2u(l1); lv.z = h2u(l2); lv.w = h2u(l3);
        *(ushort4*)(hi + (size_t)(r0 + rl) * DDIM + k0 + kq * 4) = hv;
        *(ushort4*)(lo + (size_t)(r0 + rl) * DDIM + k0 + kq * 4) = lv;
        lh_s[rl][kq * 4 + 0] = f2bf(v.x); lh_s[rl][kq * 4 + 1] = f2bf(v.y);
        lh_s[rl][kq * 4 + 2] = f2bf(v.z); lh_s[rl][kq * 4 + 3] = f2bf(v.w);
        float ssq = v.x * v.x + v.y * v.y + v.z * v.z + v.w * v.w;
        ssq += __shfl_xor(ssq, 1, 64);
        ssq += __shfl_xor(ssq, 2, 64);
        ssq += __shfl_xor(ssq, 4, 64);
        ssq += __shfl_xor(ssq, 8, 64);
        if (kq == 0) atomicAdd(&sq[r0 + rl], ssq);
    }
    __syncthreads();
#pragma unroll
    for (int it = 0; it < 16; ++it) {
        const int idx = t + 256 * it;           // 0..4095
        const int kl = idx >> 6, rl = idx & 63;
        hiT[(size_t)(k0 + kl) * R + r0 + rl] = lh_s[rl][kl];
    }
}

// ---- main GEMM pass (128i x 192j tile, fp16 2-term logits, dbuf 56KB LDS) ----
// logits = (Qh16+Ql16) @ Mh16^T ; -> P' (row-shift) + E' (masked, transposed)
// + fused rowsum/colsum via register partials + pair-shfl + few atomics.
// E via factorization: exp(lg-mn) = exp(lg-qn) * exp(qn-96) * exp(96-mn).
__global__ __launch_bounds__(256) void k_pe(
        const unsigned short* __restrict__ Qh16, const unsigned short* __restrict__ Ql16,
        const unsigned short* __restrict__ Mh16,
        const int* __restrict__ labels, const float* __restrict__ qn2,
        const float* __restrict__ mn2,
        unsigned short* __restrict__ P, unsigned short* __restrict__ ET,
        float* __restrict__ rowsum, float* __restrict__ colsum,
        int ibase, int ch, int ipg) {
    __shared__ unsigned short sA[2][2][128][BK];   // [buf][hi/lo] Q fp16, 32 KB
    __shared__ unsigned short sB[2][192][BK];      // [buf] M fp16 hi, 24 KB
    typedef unsigned short trt[32][40];
    trt* trP = (trt*)&sA[0][0][0][0];   // epilogue overlay on sA (10 KB)
    trt* trE = trP + 4;                 // next 10 KB (20 KB <= 32 KB)

    const int t = threadIdx.x, lane = t & 63, wid = t >> 6;
    const int l31 = lane & 31, lh = lane >> 5;
    const int wi = wid >> 1, wj = wid & 1;
    int ib, jb;
    if (ipg > 0) {
        const int xcd = blockIdx.x & 7, s = blockIdx.x >> 3;
        jb = s & 7; ib = xcd * ipg + (s >> 3);
    } else { jb = blockIdx.x % 8; ib = blockIdx.x / 8; }
    const int iblk = ib * 128, jblk = jb * 192;
    const int iloc0 = iblk + wi * 64;
    const int j0    = jblk + wj * 96;

    // staging: row = c>>2 (4 lanes/row -> 64B segments),
    // source chunk slot = (c ^ (c>>3)) & 3  (inverse of read oc ^ ((row>>1)&3))
    const unsigned short* gA[2] = { Qh16 + (size_t)(ibase + iblk) * DDIM,
                                    Ql16 + (size_t)(ibase + iblk) * DDIM };
    const unsigned short* gB = Mh16 + (size_t)jblk * DDIM;
    auto STAGE = [&](int b, int k0) {   // 7 gl16 per thread
#pragma unroll
        for (int h = 0; h < 2; ++h) {
#pragma unroll
            for (int it = 0; it < 2; ++it) {               // A: 512 chunks
                const int c = wid * 128 + it * 64 + lane;
                const int r = c >> 2, o = ((c ^ (c >> 3)) & 3) * 8;
                gl16(gA[h] + (size_t)r * DDIM + k0 + o, &sA[b][h][0][0] + c * 8);
            }
        }
#pragma unroll
        for (int it = 0; it < 3; ++it) {                   // B: 768 chunks
            const int c = wid * 192 + it * 64 + lane;
            const int r = c >> 2, o = ((c ^ (c >> 3)) & 3) * 8;
            gl16(gB + (size_t)r * DDIM + k0 + o, &sB[b][0][0] + c * 8);
        }
    };

    f32x16 acc[2][3] = {};
    const int ra0 = wi * 64 + l31, ra1 = ra0 + 32;
    const int rb0 = wj * 96 + l31, rb1 = rb0 + 32, rb2 = rb0 + 64;
    const int swa = (ra0 >> 1) & 3;   // same for +32/+64 row offsets
    const int swb = (rb0 >> 1) & 3;
    auto COMPUTE = [&](int b) {
#pragma unroll
        for (int t16 = 0; t16 < 2; ++t16) {
            const int oc = t16 * 2 + lh;    // k-group 0..3
            const int ka = (oc ^ swa) * 8, kb = (oc ^ swb) * 8;
            const f16x8 a0h = *(const f16x8*)&sA[b][0][ra0][ka];
            const f16x8 a1h = *(const f16x8*)&sA[b][0][ra1][ka];
            const f16x8 a0l = *(const f16x8*)&sA[b][1][ra0][ka];
            const f16x8 a1l = *(const f16x8*)&sA[b][1][ra1][ka];
            const f16x8 b0 = *(const f16x8*)&sB[b][rb0][kb];
            const f16x8 b1 = *(const f16x8*)&sB[b][rb1][kb];
            const f16x8 b2 = *(const f16x8*)&sB[b][rb2][kb];
            acc[0][0] = mfma16h(a0h, b0, acc[0][0]);
            acc[0][0] = mfma16h(a0l, b0, acc[0][0]);
            acc[0][1] = mfma16h(a0h, b1, acc[0][1]);
            acc[0][1] = mfma16h(a0l, b1, acc[0][1]);
            acc[0][2] = mfma16h(a0h, b2, acc[0][2]);
            acc[0][2] = mfma16h(a0l, b2, acc[0][2]);
            acc[1][0] = mfma16h(a1h, b0, acc[1][0]);
            acc[1][0] = mfma16h(a1l, b0, acc[1][0]);
            acc[1][1] = mfma16h(a1h, b1, acc[1][1]);
            acc[1][1] = mfma16h(a1l, b1, acc[1][1]);
            acc[1][2] = mfma16h(a1h, b2, acc[1][2]);
            acc[1][2] = mfma16h(a1l, b2, acc[1][2]);
        }
    };

    STAGE(0, 0);
    STAGE(1, BK);
    for (int s = 0; s < DDIM / BK - 1; ++s) {
        PIPE_WAIT_BAR(7);                   // buf s ready; buf s+1 in flight
        COMPUTE(s & 1);
        PIPE_BAR();                         // all waves done reading buf s
        if (s + 2 < DDIM / BK) STAGE(s & 1, (s + 2) * BK);
    }
    PIPE_WAIT_BAR(0);
    COMPUTE(1);                             // last step (odd index)
    __syncthreads();   // full drain before trP/trE overlay

    // per-lane per-tj scale: em = exp(96 - mn)
    float em3[3];
#pragma unroll
    for (int tj = 0; tj < 3; ++tj)
        em3[tj] = __expf(96.0f - 6.0f * sqrtf(mn2[j0 + tj * 32 + l31]));

    float rsum[2] = {0.f, 0.f};        // per-ti rowsum partials
    float csum[3] = {0.f, 0.f, 0.f};   // per-tj colsum partials
#pragma unroll
    for (int ti = 0; ti < 2; ++ti) {
        float qn[16], eq[16]; int lab[16];
        const int ig0 = ibase + iloc0 + ti * 32;
#pragma unroll
        for (int r = 0; r < 16; ++r) {
            const int ir = ig0 + ROWF(r);
            qn[r] = 6.0f * sqrtf(qn2[ir]);
            eq[r] = __expf(qn[r] - 96.0f);
            lab[r] = labels[ir];
        }
#pragma unroll
        for (int tj = 0; tj < 3; ++tj) {
            const int cblk = (j0 + tj * 32) >> 9;   // class of this 32-col frag
            const float em = em3[tj];
#pragma unroll
            for (int r = 0; r < 16; r += 2) {
                const float p0 = __expf(acc[ti][tj][r] - qn[r]);
                const float p1 = __expf(acc[ti][tj][r + 1] - qn[r + 1]);
                trP[wid][ROWF(r)][l31]     = f2bf(p0);
                trP[wid][ROWF(r + 1)][l31] = f2bf(p1);
                const float e0 = (lab[r] == cblk)     ? p0 * eq[r] * em     : 0.0f;
                const float e1 = (lab[r + 1] == cblk) ? p1 * eq[r + 1] * em : 0.0f;
                const unsigned pk = (unsigned)f2bf(e0) | ((unsigned)f2bf(e1) << 16);
                *(unsigned*)&trE[wid][l31][ROWF(r)] = pk;   // ROWF(r) even for even r
            }
            const int rr = lane >> 1, off = (lane & 1) * 16;
            {   // P: row rr (i-local), 16 contiguous j
                const unsigned short* lp = &trP[wid][rr][off];
                const bf16x8 w0 = *(const bf16x8*)(lp);
                const bf16x8 w1 = *(const bf16x8*)(lp + 8);
                unsigned short* prow = P + (size_t)(iloc0 + ti * 32 + rr) * STOT
                                         + j0 + tj * 32 + off;
                *(bf16x8*)(prow)     = w0;
                *(bf16x8*)(prow + 8) = w1;
                rsum[ti] += sum16(w0, w1);
            }
            {   // ET: row rr (j-local), 16 contiguous i
                const unsigned short* lp = &trE[wid][rr][off];
                const bf16x8 w0 = *(const bf16x8*)(lp);
                const bf16x8 w1 = *(const bf16x8*)(lp + 8);
                unsigned short* erow = ET + (size_t)(j0 + tj * 32 + rr) * ch
                                          + iloc0 + ti * 32 + off;
                *(bf16x8*)(erow)     = w0;
                *(bf16x8*)(erow + 8) = w1;
                csum[tj] += sum16(w0, w1);
            }
        }
    }
    // reduced-atomic delivery: pair-combine lanes (2rr, 2rr+1), one add per
    // row/col per wave (32 lanes parallel, distinct consecutive addresses).
    {
        const int rr = lane >> 1;
#pragma unroll
        for (int ti = 0; ti < 2; ++ti) {
            const float v = rsum[ti] + __shfl_xor(rsum[ti], 1, 64);
            if ((lane & 1) == 0)
                atomicAdd(&rowsum[ibase + iloc0 + ti * 32 + rr], v);
        }
#pragma unroll
        for (int tj = 0; tj < 3; ++tj) {
            const float v = csum[tj] + __shfl_xor(csum[tj], 1, 64);
            if ((lane & 1) == 0)
                atomicAdd(&colsum[j0 + tj * 32 + rr], v);
        }
    }
}

// ---- PV (dbuf, BK=64, counted-vmcnt, 128x128 tile) ----
// out = (P' @ Mhi^T) / rowsum ; grid (ch/128, 2); 4 waves (2q x 2d), wave 64x64.
__global__ __launch_bounds__(256) void k_pv(const unsigned short* __restrict__ P,
        const unsigned short* __restrict__ MhiT, const float* __restrict__ rowsum,
        float* __restrict__ out, int ibase) {
    __shared__ unsigned short sP[2][128][64];   // 32 KB
    __shared__ unsigned short sV[2][128][64];   // 32 KB
    const int t = threadIdx.x, lane = t & 63, wid = t >> 6;
    const int l31 = lane & 31, lh = lane >> 5;
    const int wq = wid >> 1, wd = wid & 1;
    const int qblk = blockIdx.x * 128, dblk = blockIdx.y * 128;
    const unsigned short* gP = P + (size_t)qblk * STOT;
    const unsigned short* gV = MhiT + (size_t)dblk * STOT;

    auto STAGE = [&](int b, int k0) {   // 8 gl16 per thread
#pragma unroll
        for (int it = 0; it < 4; ++it) {
            const int c = wid * 256 + it * 64 + lane;
            const int r = c >> 3, o = ((c & 7) ^ (r & 7)) * 8;
            gl16(gP + (size_t)r * STOT + k0 + o, &sP[b][0][0] + c * 8);
            gl16(gV + (size_t)r * STOT + k0 + o, &sV[b][0][0] + c * 8);
        }
    };

    f32x16 acc[2][2] = {};
    const int rp0 = wq * 64 + l31, rp1 = rp0 + 32;
    const int rv0 = wd * 64 + l31, rv1 = rv0 + 32;
    auto COMPUTE = [&](int b) {
#pragma unroll
        for (int t16 = 0; t16 < 4; ++t16) {
            const int oc = t16 * 2 + lh;
            const bf16x8 a0 = *(const bf16x8*)&sP[b][rp0][(oc ^ (rp0 & 7)) * 8];
            const bf16x8 a1 = *(const bf16x8*)&sP[b][rp1][(oc ^ (rp1 & 7)) * 8];
            const bf16x8 b0 = *(const bf16x8*)&sV[b][rv0][(oc ^ (rv0 & 7)) * 8];
            const bf16x8 b1 = *(const bf16x8*)&sV[b][rv1][(oc ^ (rv1 & 7)) * 8];
            acc[0][0] = mfma16(a0, b0, acc[0][0]);
            acc[0][1] = mfma16(a0, b1, acc[0][1]);
            acc[1][0] = mfma16(a1, b0, acc[1][0]);
            acc[1][1] = mfma16(a1, b1, acc[1][1]);
        }
    };

    STAGE(0, 0);
    STAGE(1, 64);
    for (int s = 0; s < STOT / 64 - 1; ++s) {
        PIPE_WAIT_BAR(8);
        COMPUTE(s & 1);
        PIPE_BAR();
        if (s + 2 < STOT / 64) STAGE(s & 1, (s + 2) * 64);
    }
    PIPE_WAIT_BAR(0);
    COMPUTE(1);                             // step 23 (odd)

    float riv[2][16];
#pragma unroll
    for (int tq = 0; tq < 2; ++tq)
#pragma unroll
        for (int r = 0; r < 16; ++r)
            riv[tq][r] = 1.f / rowsum[ibase + qblk + wq * 64 + tq * 32 + ROWF(r)];
#pragma unroll
    for (int tq = 0; tq < 2; ++tq) {
#pragma unroll
        for (int td = 0; td < 2; ++td) {
#pragma unroll
            for (int r = 0; r < 16; ++r) {
                const int ig = ibase + qblk + wq * 64 + tq * 32 + ROWF(r);
                const int od = dblk + wd * 64 + td * 32 + l31;
                out[(size_t)ig * DDIM + od] = acc[tq][td][r] * riv[tq][r];
            }
        }
    }
}

// ---- delta (dbuf, BK=64, counted-vmcnt, K=1024/block, XCD remap) ----
__global__ __launch_bounds__(256) void k_delta4(const unsigned short* __restrict__ ET,
        const unsigned short* __restrict__ QhiT,
        float* __restrict__ delta, int ibase, int ch, int ppx) {
    __shared__ unsigned short sE[2][128][64];   // 32 KB
    __shared__ unsigned short sQ[2][128][64];   // 32 KB
    const int t = threadIdx.x, lane = t & 63, wid = t >> 6;
    const int l31 = lane & 31, lh = lane >> 5;
    const int wj = wid >> 1, wd = wid & 1;
    int jb, db, kb;
    if (ppx > 0) {
        const int xcd = blockIdx.x & 7, s = blockIdx.x >> 3;
        jb = s % 12;
        const int pidx = xcd * ppx + s / 12;
        kb = pidx >> 1; db = pidx & 1;
    } else {
        jb = blockIdx.x % 12; db = (blockIdx.x / 12) & 1; kb = blockIdx.x / 24;
    }
    const int jblk = jb * 128, dblk = db * 128, i0 = kb * 1024;
    const int j0 = jblk + wj * 64, d0 = dblk + wd * 64;
    const unsigned short* gE = ET + (size_t)jblk * ch + i0;
    const unsigned short* gQ = QhiT + (size_t)dblk * NQ + ibase + i0;

    auto STAGE = [&](int b, int k0) {   // 8 gl16 per thread
#pragma unroll
        for (int it = 0; it < 4; ++it) {
            const int c = wid * 256 + it * 64 + lane;
            const int r = c >> 3, o = ((c & 7) ^ (r & 7)) * 8;
            gl16(gE + (size_t)r * ch + k0 + o, &sE[b][0][0] + c * 8);
            gl16(gQ + (size_t)r * NQ + k0 + o, &sQ[b][0][0] + c * 8);
        }
    };

    f32x16 acc[2][2] = {};
    const int re0 = wj * 64 + l31, re1 = re0 + 32;
    const int rq0 = wd * 64 + l31, rq1 = rq0 + 32;
    auto COMPUTE = [&](int b) {
#pragma unroll
        for (int t16 = 0; t16 < 4; ++t16) {
            const int oc = t16 * 2 + lh;
            const bf16x8 a0 = *(const bf16x8*)&sE[b][re0][(oc ^ (re0 & 7)) * 8];
            const bf16x8 a1 = *(const bf16x8*)&sE[b][re1][(oc ^ (re1 & 7)) * 8];
            const bf16x8 b0 = *(const bf16x8*)&sQ[b][rq0][(oc ^ (rq0 & 7)) * 8];
            const bf16x8 b1 = *(const bf16x8*)&sQ[b][rq1][(oc ^ (rq1 & 7)) * 8];
            acc[0][0] = mfma16(a0, b0, acc[0][0]);
            acc[0][1] = mfma16(a0, b1, acc[0][1]);
            acc[1][0] = mfma16(a1, b0, acc[1][0]);
            acc[1][1] = mfma16(a1, b1, acc[1][1]);
        }
    };

    STAGE(0, 0);
    STAGE(1, 64);
    for (int s = 0; s < 15; ++s) {
        PIPE_WAIT_BAR(8);
        COMPUTE(s & 1);
        PIPE_BAR();
        if (s + 2 < 16) STAGE(s & 1, (s + 2) * 64);
    }
    PIPE_WAIT_BAR(0);
    COMPUTE(1);                             // step 15 (odd)

#pragma unroll
    for (int tj = 0; tj < 2; ++tj) {
#pragma unroll
        for (int td = 0; td < 2; ++td) {
#pragma unroll
            for (int r = 0; r < 16; ++r) {
                const int jr = j0 + tj * 32 + ROWF(r);
                atomicAdd(&delta[(size_t)jr * DDIM + d0 + td * 32 + l31], acc[tj][td][r]);
            }
        }
    }
}

// ---- finalize memory: new = M + delta/colsum, row-normalize ----
__global__ void k_final(const float* __restrict__ M,
                        const float* __restrict__ delta,
                        const float* __restrict__ colsum,
                        float* __restrict__ out) {
    const int row  = blockIdx.x * 4 + (threadIdx.x >> 6);
    const int lane = threadIdx.x & 63;
    const float inv = 1.f / colsum[row];
    const float4 mv = *(const float4*)(M + (size_t)row * DDIM + lane * 4);
    const float4 dv = *(const float4*)(delta + (size_t)row * DDIM + lane * 4);
    float4 nv;
    nv.x = fmaf(dv.x, inv, mv.x);
    nv.y = fmaf(dv.y, inv, mv.y);
    nv.z = fmaf(dv.z, inv, mv.z);
    nv.w = fmaf(dv.w, inv, mv.w);
    float ss = nv.x * nv.x + nv.y * nv.y + nv.z * nv.z + nv.w * nv.w;
#pragma unroll
    for (int sh = 1; sh < 64; sh <<= 1) ss += __shfl_xor(ss, sh, 64);
    const float rn = 1.f / fmaxf(sqrtf(ss), 1e-12f);
    nv.x *= rn; nv.y *= rn; nv.z *= rn; nv.w *= rn;
    *(float4*)(out + (size_t)NQ * DDIM + (size_t)row * DDIM + lane * 4) = nv;
}

extern "C" void kernel_launch(void* const* d_in, const int* in_sizes, int n_in,
                              void* d_out, int out_size, void* d_ws, size_t ws_size,
                              hipStream_t stream) {
    const float* Q      = (const float*)d_in[0];
    const int*   labels = (const int*)d_in[1];
    const float* M      = (const float*)d_in[2];
    float* out = (float*)d_out;

    // ---- workspace layout (memset region first) ----
    char* p = (char*)d_ws;
    float* colsum = (float*)p;          p += (size_t)STOT * 4;
    float* delta  = (float*)p;          p += (size_t)STOT * DDIM * 4;
    float* qn2    = (float*)p;          p += (size_t)NQ * 4;
    float* mn2    = (float*)p;          p += (size_t)STOT * 4;
    float* rowsum = (float*)p;          p += (size_t)NQ * 4;
    const size_t zero_bytes = (size_t)(p - (char*)d_ws);
    unsigned short* Qh16 = (unsigned short*)p; p += (size_t)NQ * DDIM * 2;
    unsigned short* Ql16 = (unsigned short*)p; p += (size_t)NQ * DDIM * 2;
    unsigned short* QhiT = (unsigned short*)p; p += (size_t)NQ * DDIM * 2;
    unsigned short* Mh16 = (unsigned short*)p; p += (size_t)STOT * DDIM * 2;
    unsigned short* Ml16 = (unsigned short*)p; p += (size_t)STOT * DDIM * 2;
    unsigned short* MhiT = (unsigned short*)p; p += (size_t)STOT * DDIM * 2;
    const size_t fixed_bytes = (size_t)(p - (char*)d_ws);

    // adaptive chunking: P' (ch x 1536) + ET (1536 x ch), both bf16; ch % 1024 == 0
    int nch = 2;
    while (nch < 32 &&
           fixed_bytes + (size_t)(NQ / nch) * STOT * 2 * 2 > ws_size) nch <<= 1;
    const int ch = NQ / nch;
    unsigned short* Pbuf = (unsigned short*)p;
    unsigned short* ETb  = Pbuf + (size_t)ch * STOT;

    const int ipg    = ((ch / 128) % 8 == 0) ? (ch / 128) / 8 : 0;
    const int ksplit = ch / 1024;
    const int ppx    = ((2 * ksplit) % 8 == 0) ? (2 * ksplit) / 8 : 0;

    hipMemsetAsync(d_ws, 0, zero_bytes, stream);

    k_conv2<<<dim3(NQ / 64 + STOT / 64, 4), 256, 0, stream>>>(
        Q, M, Qh16, Ql16, QhiT, qn2, Mh16, Ml16, MhiT, mn2);

    for (int h = 0; h < nch; ++h) {
        const int ibase = h * ch;
        k_pe<<<8 * (ch / 128), 256, 0, stream>>>(Qh16, Ql16, Mh16, labels,
                                                 qn2, mn2, Pbuf, ETb, rowsum, colsum,
                                                 ibase, ch, ipg);
        k_pv<<<dim3(ch / 128, 2), 256, 0, stream>>>(Pbuf, MhiT, rowsum, out, ibase);
        k_delta4<<<24 * ksplit, 256, 0, stream>>>(ETb, QhiT, delta, ibase, ch, ppx);
    }
    k_final<<<STOT / 4, 256, 0, stream>>>(M, delta, colsum, out);
}

// Round 18
// 244.925 us; speedup vs baseline: 1.2587x; 1.0245x over previous
//
#include <hip/hip_runtime.h>
#include <math.h>

#define NQ    32768
#define DDIM  256
#define NCLS  3
#define CELLS 512
#define STOT  1536   // NCLS*CELLS
#define BK    32     // K-step for all GEMM kernels

typedef __attribute__((ext_vector_type(8)))  short bf16x8;
typedef __attribute__((ext_vector_type(8)))  _Float16 f16x8;
typedef __attribute__((ext_vector_type(16))) float f32x16;

// C-fragment row map for 32x32 MFMA: row = (r&3) + 8*(r>>2) + 4*(lane>>5)
#define ROWF(r) (((r) & 3) + 8 * ((r) >> 2) + 4 * lh)

// counted-vmcnt pipeline barriers (T4)
#define PIPE_WAIT_BAR(N) asm volatile("s_waitcnt vmcnt(" #N ")\n\ts_barrier" ::: "memory")
#define PIPE_BAR()       asm volatile("s_barrier" ::: "memory")

__device__ __forceinline__ f32x16 mfma16(bf16x8 a, bf16x8 b, f32x16 c) {
    return __builtin_amdgcn_mfma_f32_32x32x16_bf16(a, b, c, 0, 0, 0);
}
__device__ __forceinline__ f32x16 mfma16h(f16x8 a, f16x8 b, f32x16 c) {
    return __builtin_amdgcn_mfma_f32_32x32x16_f16(a, b, c, 0, 0, 0);
}
__device__ __forceinline__ unsigned short f2bf(float f) {   // RNE
    const unsigned u = __float_as_uint(f);
    return (unsigned short)((u + 0x7FFFu + ((u >> 16) & 1u)) >> 16);
}
__device__ __forceinline__ float bf2f(unsigned short b) {
    return __uint_as_float(((unsigned)b) << 16);
}
__device__ __forceinline__ unsigned short h2u(_Float16 h) {
    union { _Float16 h; unsigned short u; } v; v.h = h; return v.u;
}
// sum 16 bf16 lanes of two bf16x8 regs in fp32
__device__ __forceinline__ float sum16(bf16x8 w0, bf16x8 w1) {
    float s = 0.f;
#pragma unroll
    for (int e = 0; e < 8; ++e)
        s += bf2f((unsigned short)w0[e]) + bf2f((unsigned short)w1[e]);
    return s;
}
// async global->LDS, 16B per lane; lds dest = wave-uniform base + lane*16
__device__ __forceinline__ void gl16(const unsigned short* g, unsigned short* l) {
    __builtin_amdgcn_global_load_lds(
        (const __attribute__((address_space(1))) unsigned int*)g,
        (__attribute__((address_space(3))) unsigned int*)l, 16, 0, 0);
}

// ---- unified convert: Q and M in one launch ----
// R x 256 fp32 -> fp16 hi/lo (row-major, for QK^T; M: hi only) + transposed bf16 + row sumsq
__global__ __launch_bounds__(256) void k_conv2(const float* __restrict__ Q,
        const float* __restrict__ M,
        unsigned short* __restrict__ Qh16, unsigned short* __restrict__ Ql16,
        unsigned short* __restrict__ QhiT, float* __restrict__ qn2,
        unsigned short* __restrict__ Mh16,
        unsigned short* __restrict__ MhiT, float* __restrict__ mn2) {
    __shared__ unsigned short lh_s[64][65];
    const int bq = NQ / 64;
    const bool isQ = (int)blockIdx.x < bq;
    const float* src        = isQ ? Q    : M;
    unsigned short* hi      = isQ ? Qh16 : Mh16;
    unsigned short* hiT     = isQ ? QhiT : MhiT;
    float* sq               = isQ ? qn2  : mn2;
    const int R             = isQ ? NQ   : STOT;
    const int r0 = (isQ ? blockIdx.x : blockIdx.x - bq) * 64;
    const int k0 = blockIdx.y * 64, t = threadIdx.x;
#pragma unroll
    for (int it = 0; it < 4; ++it) {
        const int idx = t + 256 * it;
        const int rl = idx >> 4, kq = idx & 15;
        const float4 v = *(const float4*)(src + (size_t)(r0 + rl) * DDIM + k0 + kq * 4);
        const _Float16 h0 = (_Float16)v.x, h1 = (_Float16)v.y;
        const _Float16 h2 = (_Float16)v.z, h3 = (_Float16)v.w;
        ushort4 hv; hv.x = h2u(h0); hv.y = h2u(h1); hv.z = h2u(h2); hv.w = h2u(h3);
        *(ushort4*)(hi + (size_t)(r0 + rl) * DDIM + k0 + kq * 4) = hv;
        if (isQ) {
            const _Float16 l0 = (_Float16)(v.x - (float)h0), l1 = (_Float16)(v.y - (float)h1);
            const _Float16 l2 = (_Float16)(v.z - (float)h2), l3 = (_Float16)(v.w - (float)h3);
            ushort4 lv; lv.x = h2u(l0); lv.y = h2u(l1); lv.z = h2u(l2); lv.w = h2u(l3);
            *(ushort4*)(Ql16 + (size_t)(r0 + rl) * DDIM + k0 + kq * 4) = lv;
        }
        lh_s[rl][kq * 4 + 0] = f2bf(v.x); lh_s[rl][kq * 4 + 1] = f2bf(v.y);
        lh_s[rl][kq * 4 + 2] = f2bf(v.z); lh_s[rl][kq * 4 + 3] = f2bf(v.w);
        float ssq = v.x * v.x + v.y * v.y + v.z * v.z + v.w * v.w;
        ssq += __shfl_xor(ssq, 1, 64);
        ssq += __shfl_xor(ssq, 2, 64);
        ssq += __shfl_xor(ssq, 4, 64);
        ssq += __shfl_xor(ssq, 8, 64);
        if (kq == 0) atomicAdd(&sq[r0 + rl], ssq);
    }
    __syncthreads();
#pragma unroll
    for (int it = 0; it < 16; ++it) {
        const int idx = t + 256 * it;           // 0..4095
        const int kl = idx >> 6, rl = idx & 63;
        hiT[(size_t)(k0 + kl) * R + r0 + rl] = lh_s[rl][kl];
    }
}

// ---- main GEMM pass (128i x 192j tile, fp16 2-term logits, dbuf 56KB LDS) ----
// logits = (Qh16+Ql16) @ Mh16^T ; -> P' (row-shift) + E' (masked, transposed)
// + fused rowsum/colsum via trP/trE read-backs + pair-shfl + few atomics.
// E via factorization: exp(lg-mn) = exp(lg-qn) * exp(qn-96) * exp(96-mn).
__global__ __launch_bounds__(256) void k_pe(
        const unsigned short* __restrict__ Qh16, const unsigned short* __restrict__ Ql16,
        const unsigned short* __restrict__ Mh16,
        const int* __restrict__ labels, const float* __restrict__ qn2,
        const float* __restrict__ mn2,
        unsigned short* __restrict__ P, unsigned short* __restrict__ ET,
        float* __restrict__ rowsum, float* __restrict__ colsum,
        int ibase, int ch, int ipg) {
    __shared__ unsigned short sA[2][2][128][BK];   // [buf][hi/lo] Q fp16, 32 KB
    __shared__ unsigned short sB[2][192][BK];      // [buf] M fp16 hi, 24 KB
    typedef unsigned short trt[32][40];
    trt* trP = (trt*)&sA[0][0][0][0];   // epilogue overlay on sA (10 KB)
    trt* trE = trP + 4;                 // next 10 KB (20 KB <= 32 KB)

    const int t = threadIdx.x, lane = t & 63, wid = t >> 6;
    const int l31 = lane & 31, lh = lane >> 5;
    const int wi = wid >> 1, wj = wid & 1;
    int ib, jb;
    if (ipg > 0) {
        const int xcd = blockIdx.x & 7, s = blockIdx.x >> 3;
        jb = s & 7; ib = xcd * ipg + (s >> 3);
    } else { jb = blockIdx.x % 8; ib = blockIdx.x / 8; }
    const int iblk = ib * 128, jblk = jb * 192;
    const int iloc0 = iblk + wi * 64;
    const int j0    = jblk + wj * 96;

    // staging: row = c>>2 (4 lanes/row -> 64B segments),
    // source chunk slot = (c ^ (c>>3)) & 3  (inverse of read oc ^ ((row>>1)&3))
    const unsigned short* gA[2] = { Qh16 + (size_t)(ibase + iblk) * DDIM,
                                    Ql16 + (size_t)(ibase + iblk) * DDIM };
    const unsigned short* gB = Mh16 + (size_t)jblk * DDIM;
    auto STAGE = [&](int b, int k0) {   // 7 gl16 per thread
#pragma unroll
        for (int h = 0; h < 2; ++h) {
#pragma unroll
            for (int it = 0; it < 2; ++it) {               // A: 512 chunks
                const int c = wid * 128 + it * 64 + lane;
                const int r = c >> 2, o = ((c ^ (c >> 3)) & 3) * 8;
                gl16(gA[h] + (size_t)r * DDIM + k0 + o, &sA[b][h][0][0] + c * 8);
            }
        }
#pragma unroll
        for (int it = 0; it < 3; ++it) {                   // B: 768 chunks
            const int c = wid * 192 + it * 64 + lane;
            const int r = c >> 2, o = ((c ^ (c >> 3)) & 3) * 8;
            gl16(gB + (size_t)r * DDIM + k0 + o, &sB[b][0][0] + c * 8);
        }
    };

    f32x16 acc[2][3] = {};
    const int ra0 = wi * 64 + l31, ra1 = ra0 + 32;
    const int rb0 = wj * 96 + l31, rb1 = rb0 + 32, rb2 = rb0 + 64;
    const int swa = (ra0 >> 1) & 3;   // same for +32/+64 row offsets
    const int swb = (rb0 >> 1) & 3;
    auto COMPUTE = [&](int b) {
#pragma unroll
        for (int t16 = 0; t16 < 2; ++t16) {
            const int oc = t16 * 2 + lh;    // k-group 0..3
            const int ka = (oc ^ swa) * 8, kb = (oc ^ swb) * 8;
            const f16x8 a0h = *(const f16x8*)&sA[b][0][ra0][ka];
            const f16x8 a1h = *(const f16x8*)&sA[b][0][ra1][ka];
            const f16x8 a0l = *(const f16x8*)&sA[b][1][ra0][ka];
            const f16x8 a1l = *(const f16x8*)&sA[b][1][ra1][ka];
            const f16x8 b0 = *(const f16x8*)&sB[b][rb0][kb];
            const f16x8 b1 = *(const f16x8*)&sB[b][rb1][kb];
            const f16x8 b2 = *(const f16x8*)&sB[b][rb2][kb];
            acc[0][0] = mfma16h(a0h, b0, acc[0][0]);
            acc[0][0] = mfma16h(a0l, b0, acc[0][0]);
            acc[0][1] = mfma16h(a0h, b1, acc[0][1]);
            acc[0][1] = mfma16h(a0l, b1, acc[0][1]);
            acc[0][2] = mfma16h(a0h, b2, acc[0][2]);
            acc[0][2] = mfma16h(a0l, b2, acc[0][2]);
            acc[1][0] = mfma16h(a1h, b0, acc[1][0]);
            acc[1][0] = mfma16h(a1l, b0, acc[1][0]);
            acc[1][1] = mfma16h(a1h, b1, acc[1][1]);
            acc[1][1] = mfma16h(a1l, b1, acc[1][1]);
            acc[1][2] = mfma16h(a1h, b2, acc[1][2]);
            acc[1][2] = mfma16h(a1l, b2, acc[1][2]);
        }
    };

    STAGE(0, 0);
    STAGE(1, BK);
    for (int s = 0; s < DDIM / BK - 1; ++s) {
        PIPE_WAIT_BAR(7);                   // buf s ready; buf s+1 in flight
        COMPUTE(s & 1);
        PIPE_BAR();                         // all waves done reading buf s
        if (s + 2 < DDIM / BK) STAGE(s & 1, (s + 2) * BK);
    }
    PIPE_WAIT_BAR(0);
    COMPUTE(1);                             // last step (odd index)
    __syncthreads();   // full drain before trP/trE overlay

    // per-lane per-tj scale: em = exp(96 - mn)
    float em3[3];
#pragma unroll
    for (int tj = 0; tj < 3; ++tj)
        em3[tj] = __expf(96.0f - 6.0f * sqrtf(mn2[j0 + tj * 32 + l31]));

    float rsum[2] = {0.f, 0.f};        // per-ti rowsum partials
    float csum[3] = {0.f, 0.f, 0.f};   // per-tj colsum partials
#pragma unroll
    for (int ti = 0; ti < 2; ++ti) {
        float qn[16], eq[16]; int lab[16];
        const int ig0 = ibase + iloc0 + ti * 32;
#pragma unroll
        for (int r = 0; r < 16; ++r) {
            const int ir = ig0 + ROWF(r);
            qn[r] = 6.0f * sqrtf(qn2[ir]);
            eq[r] = __expf(qn[r] - 96.0f);
            lab[r] = labels[ir];
        }
#pragma unroll
        for (int tj = 0; tj < 3; ++tj) {
            const int cblk = (j0 + tj * 32) >> 9;   // class of this 32-col frag
            const float em = em3[tj];
#pragma unroll
            for (int r = 0; r < 16; r += 2) {
                const float p0 = __expf(acc[ti][tj][r] - qn[r]);
                const float p1 = __expf(acc[ti][tj][r + 1] - qn[r + 1]);
                trP[wid][ROWF(r)][l31]     = f2bf(p0);
                trP[wid][ROWF(r + 1)][l31] = f2bf(p1);
                const float e0 = (lab[r] == cblk)     ? p0 * eq[r] * em     : 0.0f;
                const float e1 = (lab[r + 1] == cblk) ? p1 * eq[r + 1] * em : 0.0f;
                const unsigned pk = (unsigned)f2bf(e0) | ((unsigned)f2bf(e1) << 16);
                *(unsigned*)&trE[wid][l31][ROWF(r)] = pk;   // ROWF(r) even for even r
            }
            const int rr = lane >> 1, off = (lane & 1) * 16;
            {   // P: row rr (i-local), 16 contiguous j
                const unsigned short* lp = &trP[wid][rr][off];
                const bf16x8 w0 = *(const bf16x8*)(lp);
                const bf16x8 w1 = *(const bf16x8*)(lp + 8);
                unsigned short* prow = P + (size_t)(iloc0 + ti * 32 + rr) * STOT
                                         + j0 + tj * 32 + off;
                *(bf16x8*)(prow)     = w0;
                *(bf16x8*)(prow + 8) = w1;
                rsum[ti] += sum16(w0, w1);
            }
            {   // ET: row rr (j-local), 16 contiguous i
                const unsigned short* lp = &trE[wid][rr][off];
                const bf16x8 w0 = *(const bf16x8*)(lp);
                const bf16x8 w1 = *(const bf16x8*)(lp + 8);
                unsigned short* erow = ET + (size_t)(j0 + tj * 32 + rr) * ch
                                          + iloc0 + ti * 32 + off;
                *(bf16x8*)(erow)     = w0;
                *(bf16x8*)(erow + 8) = w1;
                csum[tj] += sum16(w0, w1);
            }
        }
    }
    // reduced-atomic delivery: pair-combine lanes (2rr, 2rr+1), one add per
    // row/col per wave (32 lanes parallel, distinct consecutive addresses).
    {
        const int rr = lane >> 1;
#pragma unroll
        for (int ti = 0; ti < 2; ++ti) {
            const float v = rsum[ti] + __shfl_xor(rsum[ti], 1, 64);
            if ((lane & 1) == 0)
                atomicAdd(&rowsum[ibase + iloc0 + ti * 32 + rr], v);
        }
#pragma unroll
        for (int tj = 0; tj < 3; ++tj) {
            const float v = csum[tj] + __shfl_xor(csum[tj], 1, 64);
            if ((lane & 1) == 0)
                atomicAdd(&colsum[j0 + tj * 32 + rr], v);
        }
    }
}

// ---- PV (dbuf, BK=64, counted-vmcnt, 128x128 tile) ----
// out = (P' @ Mhi^T) / rowsum ; grid (ch/128, 2); 4 waves (2q x 2d), wave 64x64.
__global__ __launch_bounds__(256) void k_pv(const unsigned short* __restrict__ P,
        const unsigned short* __restrict__ MhiT, const float* __restrict__ rowsum,
        float* __restrict__ out, int ibase) {
    __shared__ unsigned short sP[2][128][64];   // 32 KB
    __shared__ unsigned short sV[2][128][64];   // 32 KB
    const int t = threadIdx.x, lane = t & 63, wid = t >> 6;
    const int l31 = lane & 31, lh = lane >> 5;
    const int wq = wid >> 1, wd = wid & 1;
    const int qblk = blockIdx.x * 128, dblk = blockIdx.y * 128;
    const unsigned short* gP = P + (size_t)qblk * STOT;
    const unsigned short* gV = MhiT + (size_t)dblk * STOT;

    auto STAGE = [&](int b, int k0) {   // 8 gl16 per thread
#pragma unroll
        for (int it = 0; it < 4; ++it) {
            const int c = wid * 256 + it * 64 + lane;
            const int r = c >> 3, o = ((c & 7) ^ (r & 7)) * 8;
            gl16(gP + (size_t)r * STOT + k0 + o, &sP[b][0][0] + c * 8);
            gl16(gV + (size_t)r * STOT + k0 + o, &sV[b][0][0] + c * 8);
        }
    };

    f32x16 acc[2][2] = {};
    const int rp0 = wq * 64 + l31, rp1 = rp0 + 32;
    const int rv0 = wd * 64 + l31, rv1 = rv0 + 32;
    auto COMPUTE = [&](int b) {
#pragma unroll
        for (int t16 = 0; t16 < 4; ++t16) {
            const int oc = t16 * 2 + lh;
            const bf16x8 a0 = *(const bf16x8*)&sP[b][rp0][(oc ^ (rp0 & 7)) * 8];
            const bf16x8 a1 = *(const bf16x8*)&sP[b][rp1][(oc ^ (rp1 & 7)) * 8];
            const bf16x8 b0 = *(const bf16x8*)&sV[b][rv0][(oc ^ (rv0 & 7)) * 8];
            const bf16x8 b1 = *(const bf16x8*)&sV[b][rv1][(oc ^ (rv1 & 7)) * 8];
            acc[0][0] = mfma16(a0, b0, acc[0][0]);
            acc[0][1] = mfma16(a0, b1, acc[0][1]);
            acc[1][0] = mfma16(a1, b0, acc[1][0]);
            acc[1][1] = mfma16(a1, b1, acc[1][1]);
        }
    };

    STAGE(0, 0);
    STAGE(1, 64);
    for (int s = 0; s < STOT / 64 - 1; ++s) {
        PIPE_WAIT_BAR(8);
        COMPUTE(s & 1);
        PIPE_BAR();
        if (s + 2 < STOT / 64) STAGE(s & 1, (s + 2) * 64);
    }
    PIPE_WAIT_BAR(0);
    COMPUTE(1);                             // step 23 (odd)

    float riv[2][16];
#pragma unroll
    for (int tq = 0; tq < 2; ++tq)
#pragma unroll
        for (int r = 0; r < 16; ++r)
            riv[tq][r] = 1.f / rowsum[ibase + qblk + wq * 64 + tq * 32 + ROWF(r)];
#pragma unroll
    for (int tq = 0; tq < 2; ++tq) {
#pragma unroll
        for (int td = 0; td < 2; ++td) {
#pragma unroll
            for (int r = 0; r < 16; ++r) {
                const int ig = ibase + qblk + wq * 64 + tq * 32 + ROWF(r);
                const int od = dblk + wd * 64 + td * 32 + l31;
                out[(size_t)ig * DDIM + od] = acc[tq][td][r] * riv[tq][r];
            }
        }
    }
}

// ---- delta (dbuf, BK=64, counted-vmcnt, K=1024/block, XCD remap) ----
__global__ __launch_bounds__(256) void k_delta4(const unsigned short* __restrict__ ET,
        const unsigned short* __restrict__ QhiT,
        float* __restrict__ delta, int ibase, int ch, int ppx) {
    __shared__ unsigned short sE[2][128][64];   // 32 KB
    __shared__ unsigned short sQ[2][128][64];   // 32 KB
    const int t = threadIdx.x, lane = t & 63, wid = t >> 6;
    const int l31 = lane & 31, lh = lane >> 5;
    const int wj = wid >> 1, wd = wid & 1;
    int jb, db, kb;
    if (ppx > 0) {
        const int xcd = blockIdx.x & 7, s = blockIdx.x >> 3;
        jb = s % 12;
        const int pidx = xcd * ppx + s / 12;
        kb = pidx >> 1; db = pidx & 1;
    } else {
        jb = blockIdx.x % 12; db = (blockIdx.x / 12) & 1; kb = blockIdx.x / 24;
    }
    const int jblk = jb * 128, dblk = db * 128, i0 = kb * 1024;
    const int j0 = jblk + wj * 64, d0 = dblk + wd * 64;
    const unsigned short* gE = ET + (size_t)jblk * ch + i0;
    const unsigned short* gQ = QhiT + (size_t)dblk * NQ + ibase + i0;

    auto STAGE = [&](int b, int k0) {   // 8 gl16 per thread
#pragma unroll
        for (int it = 0; it < 4; ++it) {
            const int c = wid * 256 + it * 64 + lane;
            const int r = c >> 3, o = ((c & 7) ^ (r & 7)) * 8;
            gl16(gE + (size_t)r * ch + k0 + o, &sE[b][0][0] + c * 8);
            gl16(gQ + (size_t)r * NQ + k0 + o, &sQ[b][0][0] + c * 8);
        }
    };

    f32x16 acc[2][2] = {};
    const int re0 = wj * 64 + l31, re1 = re0 + 32;
    const int rq0 = wd * 64 + l31, rq1 = rq0 + 32;
    auto COMPUTE = [&](int b) {
#pragma unroll
        for (int t16 = 0; t16 < 4; ++t16) {
            const int oc = t16 * 2 + lh;
            const bf16x8 a0 = *(const bf16x8*)&sE[b][re0][(oc ^ (re0 & 7)) * 8];
            const bf16x8 a1 = *(const bf16x8*)&sE[b][re1][(oc ^ (re1 & 7)) * 8];
            const bf16x8 b0 = *(const bf16x8*)&sQ[b][rq0][(oc ^ (rq0 & 7)) * 8];
            const bf16x8 b1 = *(const bf16x8*)&sQ[b][rq1][(oc ^ (rq1 & 7)) * 8];
            acc[0][0] = mfma16(a0, b0, acc[0][0]);
            acc[0][1] = mfma16(a0, b1, acc[0][1]);
            acc[1][0] = mfma16(a1, b0, acc[1][0]);
            acc[1][1] = mfma16(a1, b1, acc[1][1]);
        }
    };

    STAGE(0, 0);
    STAGE(1, 64);
    for (int s = 0; s < 15; ++s) {
        PIPE_WAIT_BAR(8);
        COMPUTE(s & 1);
        PIPE_BAR();
        if (s + 2 < 16) STAGE(s & 1, (s + 2) * 64);
    }
    PIPE_WAIT_BAR(0);
    COMPUTE(1);                             // step 15 (odd)

#pragma unroll
    for (int tj = 0; tj < 2; ++tj) {
#pragma unroll
        for (int td = 0; td < 2; ++td) {
#pragma unroll
            for (int r = 0; r < 16; ++r) {
                const int jr = j0 + tj * 32 + ROWF(r);
                atomicAdd(&delta[(size_t)jr * DDIM + d0 + td * 32 + l31], acc[tj][td][r]);
            }
        }
    }
}

// ---- finalize memory: new = M + delta/colsum, row-normalize ----
__global__ void k_final(const float* __restrict__ M,
                        const float* __restrict__ delta,
                        const float* __restrict__ colsum,
                        float* __restrict__ out) {
    const int row  = blockIdx.x * 4 + (threadIdx.x >> 6);
    const int lane = threadIdx.x & 63;
    const float inv = 1.f / colsum[row];
    const float4 mv = *(const float4*)(M + (size_t)row * DDIM + lane * 4);
    const float4 dv = *(const float4*)(delta + (size_t)row * DDIM + lane * 4);
    float4 nv;
    nv.x = fmaf(dv.x, inv, mv.x);
    nv.y = fmaf(dv.y, inv, mv.y);
    nv.z = fmaf(dv.z, inv, mv.z);
    nv.w = fmaf(dv.w, inv, mv.w);
    float ss = nv.x * nv.x + nv.y * nv.y + nv.z * nv.z + nv.w * nv.w;
#pragma unroll
    for (int sh = 1; sh < 64; sh <<= 1) ss += __shfl_xor(ss, sh, 64);
    const float rn = 1.f / fmaxf(sqrtf(ss), 1e-12f);
    nv.x *= rn; nv.y *= rn; nv.z *= rn; nv.w *= rn;
    *(float4*)(out + (size_t)NQ * DDIM + (size_t)row * DDIM + lane * 4) = nv;
}

extern "C" void kernel_launch(void* const* d_in, const int* in_sizes, int n_in,
                              void* d_out, int out_size, void* d_ws, size_t ws_size,
                              hipStream_t stream) {
    const float* Q      = (const float*)d_in[0];
    const int*   labels = (const int*)d_in[1];
    const float* M      = (const float*)d_in[2];
    float* out = (float*)d_out;

    // ---- workspace layout (memset region first) ----
    char* p = (char*)d_ws;
    float* colsum = (float*)p;          p += (size_t)STOT * 4;
    float* delta  = (float*)p;          p += (size_t)STOT * DDIM * 4;
    float* qn2    = (float*)p;          p += (size_t)NQ * 4;
    float* mn2    = (float*)p;          p += (size_t)STOT * 4;
    float* rowsum = (float*)p;          p += (size_t)NQ * 4;
    const size_t zero_bytes = (size_t)(p - (char*)d_ws);
    unsigned short* Qh16 = (unsigned short*)p; p += (size_t)NQ * DDIM * 2;
    unsigned short* Ql16 = (unsigned short*)p; p += (size_t)NQ * DDIM * 2;
    unsigned short* QhiT = (unsigned short*)p; p += (size_t)NQ * DDIM * 2;
    unsigned short* Mh16 = (unsigned short*)p; p += (size_t)STOT * DDIM * 2;
    unsigned short* MhiT = (unsigned short*)p; p += (size_t)STOT * DDIM * 2;
    const size_t fixed_bytes = (size_t)(p - (char*)d_ws);

    // adaptive chunking: P' (ch x 1536) + ET (1536 x ch), both bf16; ch % 1024 == 0
    int nch = 1;
    while (nch < 32 &&
           fixed_bytes + (size_t)(NQ / nch) * STOT * 2 * 2 > ws_size) nch <<= 1;
    const int ch = NQ / nch;
    unsigned short* Pbuf = (unsigned short*)p;
    unsigned short* ETb  = Pbuf + (size_t)ch * STOT;

    const int ipg    = ((ch / 128) % 8 == 0) ? (ch / 128) / 8 : 0;
    const int ksplit = ch / 1024;
    const int ppx    = ((2 * ksplit) % 8 == 0) ? (2 * ksplit) / 8 : 0;

    hipMemsetAsync(d_ws, 0, zero_bytes, stream);

    k_conv2<<<dim3(NQ / 64 + STOT / 64, 4), 256, 0, stream>>>(
        Q, M, Qh16, Ql16, QhiT, qn2, Mh16, MhiT, mn2);

    for (int h = 0; h < nch; ++h) {
        const int ibase = h * ch;
        k_pe<<<8 * (ch / 128), 256, 0, stream>>>(Qh16, Ql16, Mh16, labels,
                                                 qn2, mn2, Pbuf, ETb, rowsum, colsum,
                                                 ibase, ch, ipg);
        k_pv<<<dim3(ch / 128, 2), 256, 0, stream>>>(Pbuf, MhiT, rowsum, out, ibase);
        k_delta4<<<24 * ksplit, 256, 0, stream>>>(ETb, QhiT, delta, ibase, ch, ppx);
    }
    k_final<<<STOT / 4, 256, 0, stream>>>(M, delta, colsum, out);
}

// Round 20
// 244.211 us; speedup vs baseline: 1.2624x; 1.0029x over previous
//
#include <hip/hip_runtime.h>
#include <math.h>

#define NQ    32768
#define DDIM  256
#define NCLS  3
#define CELLS 512
#define STOT  1536   // NCLS*CELLS
#define BK    32     // K-step for all GEMM kernels

typedef __attribute__((ext_vector_type(8)))  short bf16x8;
typedef __attribute__((ext_vector_type(8)))  _Float16 f16x8;
typedef __attribute__((ext_vector_type(16))) float f32x16;

// C-fragment row map for 32x32 MFMA: row = (r&3) + 8*(r>>2) + 4*(lane>>5)
#define ROWF(r) (((r) & 3) + 8 * ((r) >> 2) + 4 * lh)

// counted-vmcnt pipeline barriers (T4)
#define PIPE_WAIT_BAR(N) asm volatile("s_waitcnt vmcnt(" #N ")\n\ts_barrier" ::: "memory")
#define PIPE_BAR()       asm volatile("s_barrier" ::: "memory")

__device__ __forceinline__ f32x16 mfma16(bf16x8 a, bf16x8 b, f32x16 c) {
    return __builtin_amdgcn_mfma_f32_32x32x16_bf16(a, b, c, 0, 0, 0);
}
__device__ __forceinline__ f32x16 mfma16h(f16x8 a, f16x8 b, f32x16 c) {
    return __builtin_amdgcn_mfma_f32_32x32x16_f16(a, b, c, 0, 0, 0);
}
__device__ __forceinline__ unsigned short f2bf(float f) {   // RNE
    const unsigned u = __float_as_uint(f);
    return (unsigned short)((u + 0x7FFFu + ((u >> 16) & 1u)) >> 16);
}
__device__ __forceinline__ float bf2f(unsigned short b) {
    return __uint_as_float(((unsigned)b) << 16);
}
__device__ __forceinline__ unsigned short h2u(_Float16 h) {
    union { _Float16 h; unsigned short u; } v; v.h = h; return v.u;
}
// sum 16 bf16 lanes of two bf16x8 regs in fp32
__device__ __forceinline__ float sum16(bf16x8 w0, bf16x8 w1) {
    float s = 0.f;
#pragma unroll
    for (int e = 0; e < 8; ++e)
        s += bf2f((unsigned short)w0[e]) + bf2f((unsigned short)w1[e]);
    return s;
}
// async global->LDS, 16B per lane; lds dest = wave-uniform base + lane*16
__device__ __forceinline__ void gl16(const unsigned short* g, unsigned short* l) {
    __builtin_amdgcn_global_load_lds(
        (const __attribute__((address_space(1))) unsigned int*)g,
        (__attribute__((address_space(3))) unsigned int*)l, 16, 0, 0);
}

// ---- unified convert: Q and M in one launch ----
// R x 256 fp32 -> fp16 hi/lo (row-major, for QK^T; M: hi only) + transposed bf16 + row sumsq
__global__ __launch_bounds__(256) void k_conv2(const float* __restrict__ Q,
        const float* __restrict__ M,
        unsigned short* __restrict__ Qh16, unsigned short* __restrict__ Ql16,
        unsigned short* __restrict__ QhiT, float* __restrict__ qn2,
        unsigned short* __restrict__ Mh16,
        unsigned short* __restrict__ MhiT, float* __restrict__ mn2) {
    __shared__ unsigned short lh_s[64][65];
    const int bq = NQ / 64;
    const bool isQ = (int)blockIdx.x < bq;
    const float* src        = isQ ? Q    : M;
    unsigned short* hi      = isQ ? Qh16 : Mh16;
    unsigned short* hiT     = isQ ? QhiT : MhiT;
    float* sq               = isQ ? qn2  : mn2;
    const int R             = isQ ? NQ   : STOT;
    const int r0 = (isQ ? blockIdx.x : blockIdx.x - bq) * 64;
    const int k0 = blockIdx.y * 64, t = threadIdx.x;
#pragma unroll
    for (int it = 0; it < 4; ++it) {
        const int idx = t + 256 * it;
        const int rl = idx >> 4, kq = idx & 15;
        const float4 v = *(const float4*)(src + (size_t)(r0 + rl) * DDIM + k0 + kq * 4);
        const _Float16 h0 = (_Float16)v.x, h1 = (_Float16)v.y;
        const _Float16 h2 = (_Float16)v.z, h3 = (_Float16)v.w;
        ushort4 hv; hv.x = h2u(h0); hv.y = h2u(h1); hv.z = h2u(h2); hv.w = h2u(h3);
        *(ushort4*)(hi + (size_t)(r0 + rl) * DDIM + k0 + kq * 4) = hv;
        if (isQ) {
            const _Float16 l0 = (_Float16)(v.x - (float)h0), l1 = (_Float16)(v.y - (float)h1);
            const _Float16 l2 = (_Float16)(v.z - (float)h2), l3 = (_Float16)(v.w - (float)h3);
            ushort4 lv; lv.x = h2u(l0); lv.y = h2u(l1); lv.z = h2u(l2); lv.w = h2u(l3);
            *(ushort4*)(Ql16 + (size_t)(r0 + rl) * DDIM + k0 + kq * 4) = lv;
        }
        lh_s[rl][kq * 4 + 0] = f2bf(v.x); lh_s[rl][kq * 4 + 1] = f2bf(v.y);
        lh_s[rl][kq * 4 + 2] = f2bf(v.z); lh_s[rl][kq * 4 + 3] = f2bf(v.w);
        float ssq = v.x * v.x + v.y * v.y + v.z * v.z + v.w * v.w;
        ssq += __shfl_xor(ssq, 1, 64);
        ssq += __shfl_xor(ssq, 2, 64);
        ssq += __shfl_xor(ssq, 4, 64);
        ssq += __shfl_xor(ssq, 8, 64);
        if (kq == 0) atomicAdd(&sq[r0 + rl], ssq);
    }
    __syncthreads();
#pragma unroll
    for (int it = 0; it < 16; ++it) {
        const int idx = t + 256 * it;           // 0..4095
        const int kl = idx >> 6, rl = idx & 63;
        hiT[(size_t)(k0 + kl) * R + r0 + rl] = lh_s[rl][kl];
    }
}

// ---- main GEMM pass (128i x 192j tile, fp16 2-term logits, dbuf 56KB LDS) ----
// logits = (Qh16+Ql16) @ Mh16^T ; -> P' (row-shift) + E' (masked, transposed)
// + fused rowsum/colsum via trP/trE read-backs + pair-shfl + few atomics.
// E via factorization: exp(lg-mn) = exp(lg-qn) * exp(qn-96) * exp(96-mn).
// trP/trE rows are 40 shorts (80B): half-row reads stay 16B-aligned (80=5*16);
// 4-way column-write aliasing is the structural minimum under b128 reads.
__global__ __launch_bounds__(256) void k_pe(
        const unsigned short* __restrict__ Qh16, const unsigned short* __restrict__ Ql16,
        const unsigned short* __restrict__ Mh16,
        const int* __restrict__ labels, const float* __restrict__ qn2,
        const float* __restrict__ mn2,
        unsigned short* __restrict__ P, unsigned short* __restrict__ ET,
        float* __restrict__ rowsum, float* __restrict__ colsum,
        int ibase, int ch, int ipg) {
    __shared__ unsigned short sA[2][2][128][BK];   // [buf][hi/lo] Q fp16, 32 KB
    __shared__ unsigned short sB[2][192][BK];      // [buf] M fp16 hi, 24 KB
    typedef unsigned short trt[32][40];
    trt* trP = (trt*)&sA[0][0][0][0];   // epilogue overlay on sA (10 KB)
    trt* trE = trP + 4;                 // next 10 KB (20 KB <= 32 KB)

    const int t = threadIdx.x, lane = t & 63, wid = t >> 6;
    const int l31 = lane & 31, lh = lane >> 5;
    const int wi = wid >> 1, wj = wid & 1;
    int ib, jb;
    if (ipg > 0) {
        const int xcd = blockIdx.x & 7, s = blockIdx.x >> 3;
        jb = s & 7; ib = xcd * ipg + (s >> 3);
    } else { jb = blockIdx.x % 8; ib = blockIdx.x / 8; }
    const int iblk = ib * 128, jblk = jb * 192;
    const int iloc0 = iblk + wi * 64;
    const int j0    = jblk + wj * 96;

    // staging: row = c>>2 (4 lanes/row -> 64B segments),
    // source chunk slot = (c ^ (c>>3)) & 3  (inverse of read oc ^ ((row>>1)&3))
    const unsigned short* gA[2] = { Qh16 + (size_t)(ibase + iblk) * DDIM,
                                    Ql16 + (size_t)(ibase + iblk) * DDIM };
    const unsigned short* gB = Mh16 + (size_t)jblk * DDIM;
    auto STAGE = [&](int b, int k0) {   // 7 gl16 per thread
#pragma unroll
        for (int h = 0; h < 2; ++h) {
#pragma unroll
            for (int it = 0; it < 2; ++it) {               // A: 512 chunks
                const int c = wid * 128 + it * 64 + lane;
                const int r = c >> 2, o = ((c ^ (c >> 3)) & 3) * 8;
                gl16(gA[h] + (size_t)r * DDIM + k0 + o, &sA[b][h][0][0] + c * 8);
            }
        }
#pragma unroll
        for (int it = 0; it < 3; ++it) {                   // B: 768 chunks
            const int c = wid * 192 + it * 64 + lane;
            const int r = c >> 2, o = ((c ^ (c >> 3)) & 3) * 8;
            gl16(gB + (size_t)r * DDIM + k0 + o, &sB[b][0][0] + c * 8);
        }
    };

    f32x16 acc[2][3] = {};
    const int ra0 = wi * 64 + l31, ra1 = ra0 + 32;
    const int rb0 = wj * 96 + l31, rb1 = rb0 + 32, rb2 = rb0 + 64;
    const int swa = (ra0 >> 1) & 3;   // same for +32/+64 row offsets
    const int swb = (rb0 >> 1) & 3;
    auto COMPUTE = [&](int b) {
#pragma unroll
        for (int t16 = 0; t16 < 2; ++t16) {
            const int oc = t16 * 2 + lh;    // k-group 0..3
            const int ka = (oc ^ swa) * 8, kb = (oc ^ swb) * 8;
            const f16x8 a0h = *(const f16x8*)&sA[b][0][ra0][ka];
            const f16x8 a1h = *(const f16x8*)&sA[b][0][ra1][ka];
            const f16x8 a0l = *(const f16x8*)&sA[b][1][ra0][ka];
            const f16x8 a1l = *(const f16x8*)&sA[b][1][ra1][ka];
            const f16x8 b0 = *(const f16x8*)&sB[b][rb0][kb];
            const f16x8 b1 = *(const f16x8*)&sB[b][rb1][kb];
            const f16x8 b2 = *(const f16x8*)&sB[b][rb2][kb];
            acc[0][0] = mfma16h(a0h, b0, acc[0][0]);
            acc[0][0] = mfma16h(a0l, b0, acc[0][0]);
            acc[0][1] = mfma16h(a0h, b1, acc[0][1]);
            acc[0][1] = mfma16h(a0l, b1, acc[0][1]);
            acc[0][2] = mfma16h(a0h, b2, acc[0][2]);
            acc[0][2] = mfma16h(a0l, b2, acc[0][2]);
            acc[1][0] = mfma16h(a1h, b0, acc[1][0]);
            acc[1][0] = mfma16h(a1l, b0, acc[1][0]);
            acc[1][1] = mfma16h(a1h, b1, acc[1][1]);
            acc[1][1] = mfma16h(a1l, b1, acc[1][1]);
            acc[1][2] = mfma16h(a1h, b2, acc[1][2]);
            acc[1][2] = mfma16h(a1l, b2, acc[1][2]);
        }
    };

    STAGE(0, 0);
    STAGE(1, BK);
    for (int s = 0; s < DDIM / BK - 1; ++s) {
        PIPE_WAIT_BAR(7);                   // buf s ready; buf s+1 in flight
        COMPUTE(s & 1);
        PIPE_BAR();                         // all waves done reading buf s
        if (s + 2 < DDIM / BK) STAGE(s & 1, (s + 2) * BK);
    }
    PIPE_WAIT_BAR(0);
    COMPUTE(1);                             // last step (odd index)
    __syncthreads();   // full drain before trP/trE overlay

    // per-lane per-tj scale: em = exp(96 - mn)
    float em3[3];
#pragma unroll
    for (int tj = 0; tj < 3; ++tj)
        em3[tj] = __expf(96.0f - 6.0f * sqrtf(mn2[j0 + tj * 32 + l31]));

    float rsum[2] = {0.f, 0.f};        // per-ti rowsum partials
    float csum[3] = {0.f, 0.f, 0.f};   // per-tj colsum partials
#pragma unroll
    for (int ti = 0; ti < 2; ++ti) {
        float qn[16], eq[16]; int lab[16];
        const int ig0 = ibase + iloc0 + ti * 32;
#pragma unroll
        for (int r = 0; r < 16; ++r) {
            const int ir = ig0 + ROWF(r);
            qn[r] = 6.0f * sqrtf(qn2[ir]);
            eq[r] = __expf(qn[r] - 96.0f);
            lab[r] = labels[ir];
        }
#pragma unroll
        for (int tj = 0; tj < 3; ++tj) {
            const int cblk = (j0 + tj * 32) >> 9;   // class of this 32-col frag
            const float em = em3[tj];
#pragma unroll
            for (int r = 0; r < 16; r += 2) {
                const float p0 = __expf(acc[ti][tj][r] - qn[r]);
                const float p1 = __expf(acc[ti][tj][r + 1] - qn[r + 1]);
                trP[wid][ROWF(r)][l31]     = f2bf(p0);
                trP[wid][ROWF(r + 1)][l31] = f2bf(p1);
                const float e0 = (lab[r] == cblk)     ? p0 * eq[r] * em     : 0.0f;
                const float e1 = (lab[r + 1] == cblk) ? p1 * eq[r + 1] * em : 0.0f;
                const unsigned pk = (unsigned)f2bf(e0) | ((unsigned)f2bf(e1) << 16);
                *(unsigned*)&trE[wid][l31][ROWF(r)] = pk;   // ROWF(r) even for even r
            }
            const int rr = lane >> 1, off = (lane & 1) * 16;
            {   // P: row rr (i-local), 16 contiguous j
                const unsigned short* lp = &trP[wid][rr][off];
                const bf16x8 w0 = *(const bf16x8*)(lp);
                const bf16x8 w1 = *(const bf16x8*)(lp + 8);
                unsigned short* prow = P + (size_t)(iloc0 + ti * 32 + rr) * STOT
                                         + j0 + tj * 32 + off;
                *(bf16x8*)(prow)     = w0;
                *(bf16x8*)(prow + 8) = w1;
                rsum[ti] += sum16(w0, w1);
            }
            {   // ET: row rr (j-local), 16 contiguous i
                const unsigned short* lp = &trE[wid][rr][off];
                const bf16x8 w0 = *(const bf16x8*)(lp);
                const bf16x8 w1 = *(const bf16x8*)(lp + 8);
                unsigned short* erow = ET + (size_t)(j0 + tj * 32 + rr) * ch
                                          + iloc0 + ti * 32 + off;
                *(bf16x8*)(erow)     = w0;
                *(bf16x8*)(erow + 8) = w1;
                csum[tj] += sum16(w0, w1);
            }
        }
    }
    // reduced-atomic delivery: pair-combine lanes (2rr, 2rr+1), one add per
    // row/col per wave (32 lanes parallel, distinct consecutive addresses).
    {
        const int rr = lane >> 1;
#pragma unroll
        for (int ti = 0; ti < 2; ++ti) {
            const float v = rsum[ti] + __shfl_xor(rsum[ti], 1, 64);
            if ((lane & 1) == 0)
                atomicAdd(&rowsum[ibase + iloc0 + ti * 32 + rr], v);
        }
#pragma unroll
        for (int tj = 0; tj < 3; ++tj) {
            const float v = csum[tj] + __shfl_xor(csum[tj], 1, 64);
            if ((lane & 1) == 0)
                atomicAdd(&colsum[j0 + tj * 32 + rr], v);
        }
    }
}

// ---- PV (dbuf, BK=64, counted-vmcnt, 128x128 tile) ----
// out = (P' @ Mhi^T) / rowsum ; grid (ch/128, 2); 4 waves (2q x 2d), wave 64x64.
__global__ __launch_bounds__(256) void k_pv(const unsigned short* __restrict__ P,
        const unsigned short* __restrict__ MhiT, const float* __restrict__ rowsum,
        float* __restrict__ out, int ibase) {
    __shared__ unsigned short sP[2][128][64];   // 32 KB
    __shared__ unsigned short sV[2][128][64];   // 32 KB
    const int t = threadIdx.x, lane = t & 63, wid = t >> 6;
    const int l31 = lane & 31, lh = lane >> 5;
    const int wq = wid >> 1, wd = wid & 1;
    const int qblk = blockIdx.x * 128, dblk = blockIdx.y * 128;
    const unsigned short* gP = P + (size_t)qblk * STOT;
    const unsigned short* gV = MhiT + (size_t)dblk * STOT;

    auto STAGE = [&](int b, int k0) {   // 8 gl16 per thread
#pragma unroll
        for (int it = 0; it < 4; ++it) {
            const int c = wid * 256 + it * 64 + lane;
            const int r = c >> 3, o = ((c & 7) ^ (r & 7)) * 8;
            gl16(gP + (size_t)r * STOT + k0 + o, &sP[b][0][0] + c * 8);
            gl16(gV + (size_t)r * STOT + k0 + o, &sV[b][0][0] + c * 8);
        }
    };

    f32x16 acc[2][2] = {};
    const int rp0 = wq * 64 + l31, rp1 = rp0 + 32;
    const int rv0 = wd * 64 + l31, rv1 = rv0 + 32;
    auto COMPUTE = [&](int b) {
#pragma unroll
        for (int t16 = 0; t16 < 4; ++t16) {
            const int oc = t16 * 2 + lh;
            const bf16x8 a0 = *(const bf16x8*)&sP[b][rp0][(oc ^ (rp0 & 7)) * 8];
            const bf16x8 a1 = *(const bf16x8*)&sP[b][rp1][(oc ^ (rp1 & 7)) * 8];
            const bf16x8 b0 = *(const bf16x8*)&sV[b][rv0][(oc ^ (rv0 & 7)) * 8];
            const bf16x8 b1 = *(const bf16x8*)&sV[b][rv1][(oc ^ (rv1 & 7)) * 8];
            acc[0][0] = mfma16(a0, b0, acc[0][0]);
            acc[0][1] = mfma16(a0, b1, acc[0][1]);
            acc[1][0] = mfma16(a1, b0, acc[1][0]);
            acc[1][1] = mfma16(a1, b1, acc[1][1]);
        }
    };

    STAGE(0, 0);
    STAGE(1, 64);
    for (int s = 0; s < STOT / 64 - 1; ++s) {
        PIPE_WAIT_BAR(8);
        COMPUTE(s & 1);
        PIPE_BAR();
        if (s + 2 < STOT / 64) STAGE(s & 1, (s + 2) * 64);
    }
    PIPE_WAIT_BAR(0);
    COMPUTE(1);                             // step 23 (odd)

    float riv[2][16];
#pragma unroll
    for (int tq = 0; tq < 2; ++tq)
#pragma unroll
        for (int r = 0; r < 16; ++r)
            riv[tq][r] = 1.f / rowsum[ibase + qblk + wq * 64 + tq * 32 + ROWF(r)];
#pragma unroll
    for (int tq = 0; tq < 2; ++tq) {
#pragma unroll
        for (int td = 0; td < 2; ++td) {
#pragma unroll
            for (int r = 0; r < 16; ++r) {
                const int ig = ibase + qblk + wq * 64 + tq * 32 + ROWF(r);
                const int od = dblk + wd * 64 + td * 32 + l31;
                out[(size_t)ig * DDIM + od] = acc[tq][td][r] * riv[tq][r];
            }
        }
    }
}

// ---- delta (dbuf, BK=64, counted-vmcnt, K=1024/block, XCD remap) ----
__global__ __launch_bounds__(256) void k_delta4(const unsigned short* __restrict__ ET,
        const unsigned short* __restrict__ QhiT,
        float* __restrict__ delta, int ibase, int ch, int ppx) {
    __shared__ unsigned short sE[2][128][64];   // 32 KB
    __shared__ unsigned short sQ[2][128][64];   // 32 KB
    const int t = threadIdx.x, lane = t & 63, wid = t >> 6;
    const int l31 = lane & 31, lh = lane >> 5;
    const int wj = wid >> 1, wd = wid & 1;
    int jb, db, kb;
    if (ppx > 0) {
        const int xcd = blockIdx.x & 7, s = blockIdx.x >> 3;
        jb = s % 12;
        const int pidx = xcd * ppx + s / 12;
        kb = pidx >> 1; db = pidx & 1;
    } else {
        jb = blockIdx.x % 12; db = (blockIdx.x / 12) & 1; kb = blockIdx.x / 24;
    }
    const int jblk = jb * 128, dblk = db * 128, i0 = kb * 1024;
    const int j0 = jblk + wj * 64, d0 = dblk + wd * 64;
    const unsigned short* gE = ET + (size_t)jblk * ch + i0;
    const unsigned short* gQ = QhiT + (size_t)dblk * NQ + ibase + i0;

    auto STAGE = [&](int b, int k0) {   // 8 gl16 per thread
#pragma unroll
        for (int it = 0; it < 4; ++it) {
            const int c = wid * 256 + it * 64 + lane;
            const int r = c >> 3, o = ((c & 7) ^ (r & 7)) * 8;
            gl16(gE + (size_t)r * ch + k0 + o, &sE[b][0][0] + c * 8);
            gl16(gQ + (size_t)r * NQ + k0 + o, &sQ[b][0][0] + c * 8);
        }
    };

    f32x16 acc[2][2] = {};
    const int re0 = wj * 64 + l31, re1 = re0 + 32;
    const int rq0 = wd * 64 + l31, rq1 = rq0 + 32;
    auto COMPUTE = [&](int b) {
#pragma unroll
        for (int t16 = 0; t16 < 4; ++t16) {
            const int oc = t16 * 2 + lh;
            const bf16x8 a0 = *(const bf16x8*)&sE[b][re0][(oc ^ (re0 & 7)) * 8];
            const bf16x8 a1 = *(const bf16x8*)&sE[b][re1][(oc ^ (re1 & 7)) * 8];
            const bf16x8 b0 = *(const bf16x8*)&sQ[b][rq0][(oc ^ (rq0 & 7)) * 8];
            const bf16x8 b1 = *(const bf16x8*)&sQ[b][rq1][(oc ^ (rq1 & 7)) * 8];
            acc[0][0] = mfma16(a0, b0, acc[0][0]);
            acc[0][1] = mfma16(a0, b1, acc[0][1]);
            acc[1][0] = mfma16(a1, b0, acc[1][0]);
            acc[1][1] = mfma16(a1, b1, acc[1][1]);
        }
    };

    STAGE(0, 0);
    STAGE(1, 64);
    for (int s = 0; s < 15; ++s) {
        PIPE_WAIT_BAR(8);
        COMPUTE(s & 1);
        PIPE_BAR();
        if (s + 2 < 16) STAGE(s & 1, (s + 2) * 64);
    }
    PIPE_WAIT_BAR(0);
    COMPUTE(1);                             // step 15 (odd)

#pragma unroll
    for (int tj = 0; tj < 2; ++tj) {
#pragma unroll
        for (int td = 0; td < 2; ++td) {
#pragma unroll
            for (int r = 0; r < 16; ++r) {
                const int jr = j0 + tj * 32 + ROWF(r);
                atomicAdd(&delta[(size_t)jr * DDIM + d0 + td * 32 + l31], acc[tj][td][r]);
            }
        }
    }
}

// ---- finalize memory: new = M + delta/colsum, row-normalize ----
__global__ void k_final(const float* __restrict__ M,
                        const float* __restrict__ delta,
                        const float* __restrict__ colsum,
                        float* __restrict__ out) {
    const int row  = blockIdx.x * 4 + (threadIdx.x >> 6);
    const int lane = threadIdx.x & 63;
    const float inv = 1.f / colsum[row];
    const float4 mv = *(const float4*)(M + (size_t)row * DDIM + lane * 4);
    const float4 dv = *(const float4*)(delta + (size_t)row * DDIM + lane * 4);
    float4 nv;
    nv.x = fmaf(dv.x, inv, mv.x);
    nv.y = fmaf(dv.y, inv, mv.y);
    nv.z = fmaf(dv.z, inv, mv.z);
    nv.w = fmaf(dv.w, inv, mv.w);
    float ss = nv.x * nv.x + nv.y * nv.y + nv.z * nv.z + nv.w * nv.w;
#pragma unroll
    for (int sh = 1; sh < 64; sh <<= 1) ss += __shfl_xor(ss, sh, 64);
    const float rn = 1.f / fmaxf(sqrtf(ss), 1e-12f);
    nv.x *= rn; nv.y *= rn; nv.z *= rn; nv.w *= rn;
    *(float4*)(out + (size_t)NQ * DDIM + (size_t)row * DDIM + lane * 4) = nv;
}

extern "C" void kernel_launch(void* const* d_in, const int* in_sizes, int n_in,
                              void* d_out, int out_size, void* d_ws, size_t ws_size,
                              hipStream_t stream) {
    const float* Q      = (const float*)d_in[0];
    const int*   labels = (const int*)d_in[1];
    const float* M      = (const float*)d_in[2];
    float* out = (float*)d_out;

    // ---- workspace layout (memset region first) ----
    char* p = (char*)d_ws;
    float* colsum = (float*)p;          p += (size_t)STOT * 4;
    float* delta  = (float*)p;          p += (size_t)STOT * DDIM * 4;
    float* qn2    = (float*)p;          p += (size_t)NQ * 4;
    float* mn2    = (float*)p;          p += (size_t)STOT * 4;
    float* rowsum = (float*)p;          p += (size_t)NQ * 4;
    const size_t zero_bytes = (size_t)(p - (char*)d_ws);
    unsigned short* Qh16 = (unsigned short*)p; p += (size_t)NQ * DDIM * 2;
    unsigned short* Ql16 = (unsigned short*)p; p += (size_t)NQ * DDIM * 2;
    unsigned short* QhiT = (unsigned short*)p; p += (size_t)NQ * DDIM * 2;
    unsigned short* Mh16 = (unsigned short*)p; p += (size_t)STOT * DDIM * 2;
    unsigned short* MhiT = (unsigned short*)p; p += (size_t)STOT * DDIM * 2;
    const size_t fixed_bytes = (size_t)(p - (char*)d_ws);

    // adaptive chunking: P' (ch x 1536) + ET (1536 x ch), both bf16; ch % 1024 == 0
    int nch = 1;
    while (nch < 32 &&
           fixed_bytes + (size_t)(NQ / nch) * STOT * 2 * 2 > ws_size) nch <<= 1;
    const int ch = NQ / nch;
    unsigned short* Pbuf = (unsigned short*)p;
    unsigned short* ETb  = Pbuf + (size_t)ch * STOT;

    const int ipg    = ((ch / 128) % 8 == 0) ? (ch / 128) / 8 : 0;
    const int ksplit = ch / 1024;
    const int ppx    = ((2 * ksplit) % 8 == 0) ? (2 * ksplit) / 8 : 0;

    hipMemsetAsync(d_ws, 0, zero_bytes, stream);

    k_conv2<<<dim3(NQ / 64 + STOT / 64, 4), 256, 0, stream>>>(
        Q, M, Qh16, Ql16, QhiT, qn2, Mh16, MhiT, mn2);

    for (int h = 0; h < nch; ++h) {
        const int ibase = h * ch;
        k_pe<<<8 * (ch / 128), 256, 0, stream>>>(Qh16, Ql16, Mh16, labels,
                                                 qn2, mn2, Pbuf, ETb, rowsum, colsum,
                                                 ibase, ch, ipg);
        k_pv<<<dim3(ch / 128, 2), 256, 0, stream>>>(Pbuf, MhiT, rowsum, out, ibase);
        k_delta4<<<24 * ksplit, 256, 0, stream>>>(ETb, QhiT, delta, ibase, ch, ppx);
    }
    k_final<<<STOT / 4, 256, 0, stream>>>(M, delta, colsum, out);
}